// Round 11
// baseline (1395.640 us; speedup 1.0000x reference)
//
#include <hip/hip_runtime.h>
#include <math.h>
#include <stdint.h>

#define T_DATA 20000
#define E_NO   2000
#define I_NO   500
#define SUB    16
#define TNO    200
#define NBLK   313   // ceil(20000/64)

// ---------------- workspace layout (float offsets) ----------------
// 0       ek[3200]   (s*200+t)
// 3200    ik[3200]
// 6400    hist[200]
// 6600    ewsub[16]
// 6616    we[2000]
// 8616    wi[500]
// 16384   synE[20000*16]
// 336384  synI[20000*16]
// 656384  negd[20000]
// 676384  me[2000] (int)
// 678384  mi[500]  (int)
// 678884  cmask[16](int)

// ---------------------------------------------------------------------------
// K1: per-subunit kernels, hist kernel, synapse->subunit maps, tree masks.
// ---------------------------------------------------------------------------
__global__ __launch_bounds__(256) void k_prep(
    const float* __restrict__ Ce, const float* __restrict__ Ci,
    const float* __restrict__ cosb,
    const float* __restrict__ TauE, const float* __restrict__ TauI,
    const float* __restrict__ We,  const float* __restrict__ Wi,
    const float* __restrict__ De,  const float* __restrict__ Di,
    const float* __restrict__ Wsub, const float* __restrict__ Whist,
    const int* __restrict__ Cden,
    float* __restrict__ ws_ek, float* __restrict__ ws_ik,
    float* __restrict__ ws_hist, float* __restrict__ ws_ewsub,
    float* __restrict__ ws_we, float* __restrict__ ws_wi,
    int* __restrict__ ws_me, int* __restrict__ ws_mi, int* __restrict__ ws_cmask,
    float* __restrict__ out_filt) {
  int tid = threadIdx.x;
  for (int idx = tid; idx < SUB * TNO; idx += 256) {
    int s = idx / TNO;
    float tf = (float)(idx % TNO);
    float te  = fmaxf(tf - expf(De[s]), 0.f);
    float tte = te / expf(TauE[s]);
    float ekv = tte * expf(-tte) * expf(We[s]);
    float ti_ = fmaxf(tf - expf(Di[s]), 0.f);
    float tti = ti_ / expf(TauI[s]);
    float ikv = -(tti * expf(-tti) * expf(Wi[s]));
    ws_ek[idx] = ekv;
    ws_ik[idx] = ikv;
    out_filt[idx] = ekv;            // rows 0..15
    out_filt[3200 + idx] = ikv;     // rows 16..31
  }
  for (int t = tid; t < TNO; t += 256) {
    float h = 0.f;
    for (int b = 0; b < 16; ++b) h = fmaf(Whist[b], cosb[b * TNO + t], h);
    ws_hist[t] = h;
    out_filt[6400 + t] = h;         // row 32 (unflipped)
  }
  for (int e = tid; e < E_NO; e += 256) {
    int m = 0; float w = 0.f;
    for (int s = 0; s < SUB; ++s) {
      float v = Ce[s * E_NO + e];
      if (w == 0.f && v != 0.f) { m = s; w = v; }
    }
    ws_me[e] = m; ws_we[e] = w;
  }
  for (int e = tid; e < I_NO; e += 256) {
    int m = 0; float w = 0.f;
    for (int s = 0; s < SUB; ++s) {
      float v = Ci[s * I_NO + e];
      if (w == 0.f && v != 0.f) { m = s; w = v; }
    }
    ws_mi[e] = m; ws_wi[e] = w;
  }
  if (tid < SUB) {
    ws_ewsub[tid] = expf(Wsub[tid]);
    int msk = 0;
    for (int j = 0; j < SUB; ++j)
      if (Cden[tid * SUB + j] == 1) msk |= (1 << j);
    ws_cmask[tid] = msk;
  }
}

// ---------------------------------------------------------------------------
// K2: synapse aggregation -> synE/synI [20000][16]. Deterministic.
// ---------------------------------------------------------------------------
__global__ __launch_bounds__(256) void k_agg(
    const float4* __restrict__ Se4, const float4* __restrict__ Si4,
    const int* __restrict__ me, const float* __restrict__ we,
    const int* __restrict__ mi, const float* __restrict__ wi,
    float* __restrict__ synE, float* __restrict__ synI) {
  __shared__ float bins[4][64][33];
  int tid = threadIdx.x, wid = tid >> 6, l = tid & 63;
  int gw = blockIdx.x * 4 + wid;
  for (int r = 0; r < 4; ++r) {
    int t = gw * 4 + r;
#pragma unroll
    for (int s = 0; s < 32; ++s) bins[wid][l][s] = 0.f;
    for (int i = 0; i < 8; ++i) {
      int idx = i * 64 + l;
      if (idx < 500) {
        float4 v = Se4[(size_t)t * 500 + idx];
        int e0 = idx * 4;
        if (v.x != 0.f) bins[wid][l][me[e0 + 0]] += v.x * we[e0 + 0];
        if (v.y != 0.f) bins[wid][l][me[e0 + 1]] += v.y * we[e0 + 1];
        if (v.z != 0.f) bins[wid][l][me[e0 + 2]] += v.z * we[e0 + 2];
        if (v.w != 0.f) bins[wid][l][me[e0 + 3]] += v.w * we[e0 + 3];
      }
    }
    for (int i = 0; i < 2; ++i) {
      int idx = i * 64 + l;
      if (idx < 125) {
        float4 v = Si4[(size_t)t * 125 + idx];
        int e0 = idx * 4;
        if (v.x != 0.f) bins[wid][l][16 + mi[e0 + 0]] += v.x * wi[e0 + 0];
        if (v.y != 0.f) bins[wid][l][16 + mi[e0 + 1]] += v.y * wi[e0 + 1];
        if (v.z != 0.f) bins[wid][l][16 + mi[e0 + 2]] += v.z * wi[e0 + 2];
        if (v.w != 0.f) bins[wid][l][16 + mi[e0 + 3]] += v.w * wi[e0 + 3];
      }
    }
    __syncthreads();
    if (l < 32) {
      float a = 0.f;
      for (int k = 0; k < 64; ++k) a += bins[wid][k][l];
      if (l < 16) synE[(size_t)t * 16 + l] = a;
      else        synI[(size_t)t * 16 + (l - 16)] = a;
    }
    __syncthreads();
  }
}

// ---------------------------------------------------------------------------
// K3: causal filtering + dendritic tree -> negd[t] = -drive[t].
// ---------------------------------------------------------------------------
__global__ __launch_bounds__(64) void k_filt(
    const float* __restrict__ synE, const float* __restrict__ synI,
    const float* __restrict__ ek_ws, const float* __restrict__ ik_ws,
    const float* __restrict__ theta, const float* __restrict__ ewsub,
    const int* __restrict__ cmask,
    float* __restrict__ negd) {
  __shared__ float sE[264 * 17];
  __shared__ float sI[264 * 17];
  __shared__ float ekl[TNO * 16];
  __shared__ float ikl[TNO * 16];
  int l = threadIdx.x;
  int t0 = blockIdx.x * 64;
  for (int idx = l; idx < 264 * 16; idx += 64) {
    int row = idx >> 4, s = idx & 15;
    int g = t0 - 200 + row;
    bool ok = (g >= 0) && (g < T_DATA);
    sE[row * 17 + s] = ok ? synE[(size_t)g * 16 + s] : 0.f;
    sI[row * 17 + s] = ok ? synI[(size_t)g * 16 + s] : 0.f;
  }
  for (int idx = l; idx < SUB * TNO; idx += 64) {
    int s = idx / TNO, j = idx % TNO;
    ekl[j * 16 + s] = ek_ws[idx];
    ikl[j * 16 + s] = ik_ws[idx];
  }
  __syncthreads();
  int t = t0 + l;
  float acc[16];
#pragma unroll
  for (int s = 0; s < 16; ++s) acc[s] = 0.f;
  for (int j = 0; j < TNO; ++j) {
    int base = (l + 199 - j) * 17;
    int kb = j * 16;
#pragma unroll
    for (int s = 0; s < 16; ++s)
      acc[s] = fmaf(ekl[kb + s], sE[base + s], fmaf(ikl[kb + s], sI[base + s], acc[s]));
  }
  float th[16], ew[16]; int cm[16];
#pragma unroll
  for (int s = 0; s < 16; ++s) { th[s] = theta[s]; ew[s] = ewsub[s]; cm[s] = cmask[s]; }
  float val[16];
#pragma unroll
  for (int s = 0; s < 16; ++s) val[s] = 0.f;
#pragma unroll
  for (int sidx = 15; sidx >= 1; --sidx) {
    float sum = acc[sidx] + th[sidx];
#pragma unroll
    for (int j = 0; j < 16; ++j)
      if ((cm[sidx] >> j) & 1) sum += val[j] * ew[j];
    val[sidx] = tanhf(sum);
  }
  float drive = acc[0] + th[0];
#pragma unroll
  for (int j = 0; j < 16; ++j)
    if ((cm[0] >> j) & 1) drive += val[j] * ew[j];
  if (t < T_DATA) negd[t] = -drive;
}

// ---------------------------------------------------------------------------
// K4: sequential spike scan. 1 workgroup, 4 waves (one per SIMD).
// ROUND 11: R9's 4-step lookahead math re-expressed in R8's proven code
// style: 8 speculative ballots via FOUR small 2-cmp asm blocks (scheduler
// keeps freedom), selection tree as plain-C ternaries on "=s" u64s (compiler
// emits s_cselect chains overlapped with cmp issue), tail = 4 parallel cvt
// + 4 fmaf. One VALU->SALU->VALU round trip now amortized over 4 steps.
// R9's failure was the monolithic 27-inst asm volatile (365cyc/quad), not
// the math. Combo tap registers back for the Xab/Xac/Xbc/Xabc variants.
// ---------------------------------------------------------------------------
__global__
__attribute__((amdgpu_flat_work_group_size(256, 256), amdgpu_waves_per_eu(1, 1)))
void k_scan(
    const float* __restrict__ hist, const float* __restrict__ negd,
    float* __restrict__ out_spk) {
  __shared__ float hpad[328];        // [0..63]=0, [64..263]=h[0..199], [264..327]=0
  __shared__ unsigned long long mring[8];  // per-block spike masks, slot n&7
  __shared__ float deepb[2][3][64];  // parity double-buffered deep partials
  int tid = threadIdx.x, wid = tid >> 6, l = tid & 63;
  for (int i = tid; i < 328; i += 256) hpad[i] = (i >= 64 && i < 264) ? hist[i - 64] : 0.f;
  if (tid < 8) mring[tid] = 0ull;
  for (int i = tid; i < 2 * 3 * 64; i += 256) (&deepb[0][0][0])[i] = 0.f;
  __syncthreads();

  // wave0: h(j) = hpad[l + j].  chain step i adds h(63-i); boundary tap i
  // adds h(127-i).
  float h0=0,h1=0,h2=0,h3=0,h4=0,h5=0,h6=0,h7=0,h8=0,h9=0,h10=0,h11=0,h12=0,h13=0,h14=0,h15=0,
        h16=0,h17=0,h18=0,h19=0,h20=0,h21=0,h22=0,h23=0,h24=0,h25=0,h26=0,h27=0,h28=0,h29=0,h30=0,h31=0,
        h32=0,h33=0,h34=0,h35=0,h36=0,h37=0,h38=0,h39=0,h40=0,h41=0,h42=0,h43=0,h44=0,h45=0,h46=0,h47=0,
        h48=0,h49=0,h50=0,h51=0,h52=0,h53=0,h54=0,h55=0,h56=0,h57=0,h58=0,h59=0,h60=0,h61=0,h62=0,h63=0,
        h64=0,h65=0,h66=0,h67=0,h68=0,h69=0,h70=0,h71=0,h72=0,h73=0,h74=0,h75=0,h76=0,h77=0,h78=0,h79=0,
        h80=0,h81=0,h82=0,h83=0,h84=0,h85=0,h86=0,h87=0,h88=0,h89=0,h90=0,h91=0,h92=0,h93=0,h94=0,h95=0,
        h96=0,h97=0,h98=0,h99=0,h100=0,h101=0,h102=0,h103=0,h104=0,h105=0,h106=0,h107=0,h108=0,h109=0,h110=0,h111=0,
        h112=0,h113=0,h114=0,h115=0,h116=0,h117=0,h118=0,h119=0,h120=0,h121=0,h122=0,h123=0,h124=0,h125=0,h126=0,h127=0;
  // per-quad combo tap vectors (block-invariant)
  float cab0=0,cac0=0,cbc0=0,cabc0=0, cab1=0,cac1=0,cbc1=0,cabc1=0,
        cab2=0,cac2=0,cbc2=0,cabc2=0, cab3=0,cac3=0,cbc3=0,cabc3=0,
        cab4=0,cac4=0,cbc4=0,cabc4=0, cab5=0,cac5=0,cbc5=0,cabc5=0,
        cab6=0,cac6=0,cbc6=0,cabc6=0, cab7=0,cac7=0,cbc7=0,cabc7=0,
        cab8=0,cac8=0,cbc8=0,cabc8=0, cab9=0,cac9=0,cbc9=0,cabc9=0,
        cab10=0,cac10=0,cbc10=0,cabc10=0, cab11=0,cac11=0,cbc11=0,cabc11=0,
        cab12=0,cac12=0,cbc12=0,cabc12=0, cab13=0,cac13=0,cbc13=0,cabc13=0,
        cab14=0,cac14=0,cbc14=0,cabc14=0, cab15=0,cac15=0,cbc15=0,cabc15=0;
  // deep-wave tap registers: hd(j) = hpad[dbase + l + j]
  float hd0=0,hd1=0,hd2=0,hd3=0,hd4=0,hd5=0,hd6=0,hd7=0,hd8=0,hd9=0,hd10=0,hd11=0,hd12=0,hd13=0,hd14=0,hd15=0,
        hd16=0,hd17=0,hd18=0,hd19=0,hd20=0,hd21=0,hd22=0,hd23=0,hd24=0,hd25=0,hd26=0,hd27=0,hd28=0,hd29=0,hd30=0,hd31=0,
        hd32=0,hd33=0,hd34=0,hd35=0,hd36=0,hd37=0,hd38=0,hd39=0,hd40=0,hd41=0,hd42=0,hd43=0,hd44=0,hd45=0;
  if (wid == 0) {
#define LD(j) h##j = hpad[l + j];
    LD(0)LD(1)LD(2)LD(3)LD(4)LD(5)LD(6)LD(7)LD(8)LD(9)LD(10)LD(11)LD(12)LD(13)LD(14)LD(15)
    LD(16)LD(17)LD(18)LD(19)LD(20)LD(21)LD(22)LD(23)LD(24)LD(25)LD(26)LD(27)LD(28)LD(29)LD(30)LD(31)
    LD(32)LD(33)LD(34)LD(35)LD(36)LD(37)LD(38)LD(39)LD(40)LD(41)LD(42)LD(43)LD(44)LD(45)LD(46)LD(47)
    LD(48)LD(49)LD(50)LD(51)LD(52)LD(53)LD(54)LD(55)LD(56)LD(57)LD(58)LD(59)LD(60)LD(61)LD(62)LD(63)
    LD(64)LD(65)LD(66)LD(67)LD(68)LD(69)LD(70)LD(71)LD(72)LD(73)LD(74)LD(75)LD(76)LD(77)LD(78)LD(79)
    LD(80)LD(81)LD(82)LD(83)LD(84)LD(85)LD(86)LD(87)LD(88)LD(89)LD(90)LD(91)LD(92)LD(93)LD(94)LD(95)
    LD(96)LD(97)LD(98)LD(99)LD(100)LD(101)LD(102)LD(103)LD(104)LD(105)LD(106)LD(107)LD(108)LD(109)LD(110)LD(111)
    LD(112)LD(113)LD(114)LD(115)LD(116)LD(117)LD(118)LD(119)LD(120)LD(121)LD(122)LD(123)LD(124)LD(125)LD(126)LD(127)
#undef LD
#define MKC(q, hA, hB, hC) cab##q = hA + hB; cac##q = hA + hC; cbc##q = hB + hC; cabc##q = cab##q + hC;
    MKC(0,h63,h62,h61)   MKC(1,h59,h58,h57)   MKC(2,h55,h54,h53)   MKC(3,h51,h50,h49)
    MKC(4,h47,h46,h45)   MKC(5,h43,h42,h41)   MKC(6,h39,h38,h37)   MKC(7,h35,h34,h33)
    MKC(8,h31,h30,h29)   MKC(9,h27,h26,h25)   MKC(10,h23,h22,h21)  MKC(11,h19,h18,h17)
    MKC(12,h15,h14,h13)  MKC(13,h11,h10,h9)   MKC(14,h7,h6,h5)     MKC(15,h3,h2,h1)
#undef MKC
  } else {
    int dbase = (wid == 2) ? 174 : (wid == 3) ? 219 : 128;
#define LHD(j) hd##j = hpad[dbase + l + j];
    LHD(0)LHD(1)LHD(2)LHD(3)LHD(4)LHD(5)LHD(6)LHD(7)LHD(8)LHD(9)LHD(10)LHD(11)LHD(12)LHD(13)LHD(14)LHD(15)
    LHD(16)LHD(17)LHD(18)LHD(19)LHD(20)LHD(21)LHD(22)LHD(23)LHD(24)LHD(25)LHD(26)LHD(27)LHD(28)LHD(29)LHD(30)LHD(31)
    LHD(32)LHD(33)LHD(34)LHD(35)LHD(36)LHD(37)LHD(38)LHD(39)LHD(40)LHD(41)LHD(42)LHD(43)LHD(44)LHD(45)
#undef LHD
  }

  unsigned long long mask_prev = 0ull;
  float ndv = (wid == 0) ? negd[l] : 0.f;

  for (int n = 0; n < NBLK; ++n) {
    int t0 = n * 64;
    if (wid == 0) {
      int tn = t0 + 64 + l;
      float ndnext = (tn < T_DATA) ? negd[tn] : INFINITY;
      int par = n & 1;
      float X = deepb[par][0][l] + deepb[par][1][l] + deepb[par][2][l];
      // boundary conv: prev-block bit i adds h(127-i) — pure register math
      {
        float a0 = 0.f, a1 = 0.f, a2 = 0.f, a3 = 0.f;
#define BD(i, hv, acc) acc = fmaf((float)((mask_prev >> (i)) & 1ull), hv, acc);
        BD(0,h127,a0)BD(1,h126,a1)BD(2,h125,a2)BD(3,h124,a3)
        BD(4,h123,a0)BD(5,h122,a1)BD(6,h121,a2)BD(7,h120,a3)
        BD(8,h119,a0)BD(9,h118,a1)BD(10,h117,a2)BD(11,h116,a3)
        BD(12,h115,a0)BD(13,h114,a1)BD(14,h113,a2)BD(15,h112,a3)
        BD(16,h111,a0)BD(17,h110,a1)BD(18,h109,a2)BD(19,h108,a3)
        BD(20,h107,a0)BD(21,h106,a1)BD(22,h105,a2)BD(23,h104,a3)
        BD(24,h103,a0)BD(25,h102,a1)BD(26,h101,a2)BD(27,h100,a3)
        BD(28,h99,a0)BD(29,h98,a1)BD(30,h97,a2)BD(31,h96,a3)
        BD(32,h95,a0)BD(33,h94,a1)BD(34,h93,a2)BD(35,h92,a3)
        BD(36,h91,a0)BD(37,h90,a1)BD(38,h89,a2)BD(39,h88,a3)
        BD(40,h87,a0)BD(41,h86,a1)BD(42,h85,a2)BD(43,h84,a3)
        BD(44,h83,a0)BD(45,h82,a1)BD(46,h81,a2)BD(47,h80,a3)
        BD(48,h79,a0)BD(49,h78,a1)BD(50,h77,a2)BD(51,h76,a3)
        BD(52,h75,a0)BD(53,h74,a1)BD(54,h73,a2)BD(55,h72,a3)
        BD(56,h71,a0)BD(57,h70,a1)BD(58,h69,a2)BD(59,h68,a3)
        BD(60,h67,a0)BD(61,h66,a1)BD(62,h65,a2)BD(63,h64,a3)
#undef BD
        X += (a0 + a1) + (a2 + a3);
      }
      // 4-step lookahead chain: 16 quads cover steps 0..63.
      unsigned long long msk = 0ull;
#define CH4(i, hvA, hvB, hvC, hvD, cAB, cAC, cBC, cABC) { \
      float Xa = X + (hvA), Xb = X + (hvB), Xc = X + (hvC); \
      float Xab = X + (cAB), Xac = X + (cAC), Xbc = X + (cBC), Xabc = X + (cABC); \
      unsigned long long bm0, bmA, bmB, bmAB, bmC, bmAC, bmBC, bmABC; \
      asm("v_cmp_gt_f32 %0, %2, %4\n\t" \
          "v_cmp_gt_f32 %1, %3, %4" \
          : "=s"(bm0), "=s"(bmA) : "v"(X), "v"(Xa), "v"(ndv)); \
      asm("v_cmp_gt_f32 %0, %2, %4\n\t" \
          "v_cmp_gt_f32 %1, %3, %4" \
          : "=s"(bmB), "=s"(bmAB) : "v"(Xb), "v"(Xab), "v"(ndv)); \
      asm("v_cmp_gt_f32 %0, %2, %4\n\t" \
          "v_cmp_gt_f32 %1, %3, %4" \
          : "=s"(bmC), "=s"(bmAC) : "v"(Xc), "v"(Xac), "v"(ndv)); \
      asm("v_cmp_gt_f32 %0, %2, %4\n\t" \
          "v_cmp_gt_f32 %1, %3, %4" \
          : "=s"(bmBC), "=s"(bmABC) : "v"(Xbc), "v"(Xabc), "v"(ndv)); \
      unsigned long long s0 = (bm0 >> (i)) & 1ull; \
      unsigned long long selA = s0 ? bmA : bm0; \
      unsigned long long s1 = (selA >> ((i) + 1)) & 1ull; \
      unsigned long long sel2 = s1 ? (s0 ? bmAB : bmB) : selA; \
      unsigned long long s2 = (sel2 >> ((i) + 2)) & 1ull; \
      unsigned long long sel3 = s2 ? (s1 ? (s0 ? bmABC : bmBC) \
                                        : (s0 ? bmAC : bmC)) : sel2; \
      unsigned long long s3 = (sel3 >> ((i) + 3)) & 1ull; \
      float f0 = (float)(unsigned)s0, f1 = (float)(unsigned)s1; \
      float f2 = (float)(unsigned)s2, f3 = (float)(unsigned)s3; \
      X = fmaf(f0, (hvA), X); \
      X = fmaf(f1, (hvB), X); \
      X = fmaf(f2, (hvC), X); \
      X = fmaf(f3, (hvD), X); \
      msk |= (s0 << (i)) | (s1 << ((i) + 1)) | (s2 << ((i) + 2)) | (s3 << ((i) + 3)); }
      CH4(0,  h63,h62,h61,h60, cab0,cac0,cbc0,cabc0)
      CH4(4,  h59,h58,h57,h56, cab1,cac1,cbc1,cabc1)
      CH4(8,  h55,h54,h53,h52, cab2,cac2,cbc2,cabc2)
      CH4(12, h51,h50,h49,h48, cab3,cac3,cbc3,cabc3)
      CH4(16, h47,h46,h45,h44, cab4,cac4,cbc4,cabc4)
      CH4(20, h43,h42,h41,h40, cab5,cac5,cbc5,cabc5)
      CH4(24, h39,h38,h37,h36, cab6,cac6,cbc6,cabc6)
      CH4(28, h35,h34,h33,h32, cab7,cac7,cbc7,cabc7)
      CH4(32, h31,h30,h29,h28, cab8,cac8,cbc8,cabc8)
      CH4(36, h27,h26,h25,h24, cab9,cac9,cbc9,cabc9)
      CH4(40, h23,h22,h21,h20, cab10,cac10,cbc10,cabc10)
      CH4(44, h19,h18,h17,h16, cab11,cac11,cbc11,cabc11)
      CH4(48, h15,h14,h13,h12, cab12,cac12,cbc12,cabc12)
      CH4(52, h11,h10,h9,h8,   cab13,cac13,cbc13,cabc13)
      CH4(56, h7,h6,h5,h4,     cab14,cac14,cbc14,cabc14)
      CH4(60, h3,h2,h1,h0,     cab15,cac15,cbc15,cabc15)
#undef CH4
      // publish: spike output + block mask
      float myspk = (float)((msk >> l) & 1ull);
      int t = t0 + l;
      if (t < T_DATA) out_spk[t] = myspk;
      if (l == 0) mring[n & 7] = msk;
      mask_prev = msk;
      ndv = ndnext;
    } else {
      // deep feedback for block n+1 from spike bitmasks of blocks n-1..n-3.
      unsigned long long M1 = mring[(n + 7) & 7];
      unsigned long long M2 = mring[(n + 6) & 7];
      unsigned long long M3 = mring[(n + 5) & 7];
      M1 = ((unsigned long long)__builtin_amdgcn_readfirstlane((unsigned)(M1 >> 32)) << 32)
           | (unsigned)__builtin_amdgcn_readfirstlane((unsigned)M1);
      M2 = ((unsigned long long)__builtin_amdgcn_readfirstlane((unsigned)(M2 >> 32)) << 32)
           | (unsigned)__builtin_amdgcn_readfirstlane((unsigned)M2);
      M3 = ((unsigned long long)__builtin_amdgcn_readfirstlane((unsigned)(M3 >> 32)) << 32)
           | (unsigned)__builtin_amdgcn_readfirstlane((unsigned)M3);
      float a0 = 0.f, a1 = 0.f, a2 = 0.f, a3 = 0.f;
#define DT(j, M, b, acc) acc = fmaf((float)(((M) >> (b)) & 1ull), hd##j, acc);
      if (wid == 1) {
        DT(0,M1,63,a0)DT(1,M1,62,a1)DT(2,M1,61,a2)DT(3,M1,60,a3)
        DT(4,M1,59,a0)DT(5,M1,58,a1)DT(6,M1,57,a2)DT(7,M1,56,a3)
        DT(8,M1,55,a0)DT(9,M1,54,a1)DT(10,M1,53,a2)DT(11,M1,52,a3)
        DT(12,M1,51,a0)DT(13,M1,50,a1)DT(14,M1,49,a2)DT(15,M1,48,a3)
        DT(16,M1,47,a0)DT(17,M1,46,a1)DT(18,M1,45,a2)DT(19,M1,44,a3)
        DT(20,M1,43,a0)DT(21,M1,42,a1)DT(22,M1,41,a2)DT(23,M1,40,a3)
        DT(24,M1,39,a0)DT(25,M1,38,a1)DT(26,M1,37,a2)DT(27,M1,36,a3)
        DT(28,M1,35,a0)DT(29,M1,34,a1)DT(30,M1,33,a2)DT(31,M1,32,a3)
        DT(32,M1,31,a0)DT(33,M1,30,a1)DT(34,M1,29,a2)DT(35,M1,28,a3)
        DT(36,M1,27,a0)DT(37,M1,26,a1)DT(38,M1,25,a2)DT(39,M1,24,a3)
        DT(40,M1,23,a0)DT(41,M1,22,a1)DT(42,M1,21,a2)DT(43,M1,20,a3)
        DT(44,M1,19,a0)DT(45,M1,18,a1)
      } else if (wid == 2) {
        DT(0,M1,17,a0)DT(1,M1,16,a1)DT(2,M1,15,a2)DT(3,M1,14,a3)
        DT(4,M1,13,a0)DT(5,M1,12,a1)DT(6,M1,11,a2)DT(7,M1,10,a3)
        DT(8,M1,9,a0)DT(9,M1,8,a1)DT(10,M1,7,a2)DT(11,M1,6,a3)
        DT(12,M1,5,a0)DT(13,M1,4,a1)DT(14,M1,3,a2)DT(15,M1,2,a3)
        DT(16,M1,1,a0)DT(17,M1,0,a1)
        DT(18,M2,63,a2)DT(19,M2,62,a3)
        DT(20,M2,61,a0)DT(21,M2,60,a1)DT(22,M2,59,a2)DT(23,M2,58,a3)
        DT(24,M2,57,a0)DT(25,M2,56,a1)DT(26,M2,55,a2)DT(27,M2,54,a3)
        DT(28,M2,53,a0)DT(29,M2,52,a1)DT(30,M2,51,a2)DT(31,M2,50,a3)
        DT(32,M2,49,a0)DT(33,M2,48,a1)DT(34,M2,47,a2)DT(35,M2,46,a3)
        DT(36,M2,45,a0)DT(37,M2,44,a1)DT(38,M2,43,a2)DT(39,M2,42,a3)
        DT(40,M2,41,a0)DT(41,M2,40,a1)DT(42,M2,39,a2)DT(43,M2,38,a3)
        DT(44,M2,37,a0)
      } else {
        DT(0,M2,36,a0)DT(1,M2,35,a1)DT(2,M2,34,a2)DT(3,M2,33,a3)
        DT(4,M2,32,a0)DT(5,M2,31,a1)DT(6,M2,30,a2)DT(7,M2,29,a3)
        DT(8,M2,28,a0)DT(9,M2,27,a1)DT(10,M2,26,a2)DT(11,M2,25,a3)
        DT(12,M2,24,a0)DT(13,M2,23,a1)DT(14,M2,22,a2)DT(15,M2,21,a3)
        DT(16,M2,20,a0)DT(17,M2,19,a1)DT(18,M2,18,a2)DT(19,M2,17,a3)
        DT(20,M2,16,a0)DT(21,M2,15,a1)DT(22,M2,14,a2)DT(23,M2,13,a3)
        DT(24,M2,12,a0)DT(25,M2,11,a1)DT(26,M2,10,a2)DT(27,M2,9,a3)
        DT(28,M2,8,a0)DT(29,M2,7,a1)DT(30,M2,6,a2)DT(31,M2,5,a3)
        DT(32,M2,4,a0)DT(33,M2,3,a1)DT(34,M2,2,a2)DT(35,M2,1,a3)
        DT(36,M2,0,a0)
        DT(37,M3,63,a1)DT(38,M3,62,a2)DT(39,M3,61,a3)
        DT(40,M3,60,a0)DT(41,M3,59,a1)DT(42,M3,58,a2)DT(43,M3,57,a3)
        DT(44,M3,56,a0)
      }
#undef DT
      deepb[(n + 1) & 1][wid - 1][l] = (a0 + a1) + (a2 + a3);
    }
    __syncthreads();
  }
}

// ---------------------------------------------------------------------------
extern "C" void kernel_launch(void* const* d_in, const int* in_sizes, int n_in,
                              void* d_out, int out_size, void* d_ws, size_t ws_size,
                              hipStream_t stream) {
  const float* S_e      = (const float*)d_in[0];
  const float* S_i      = (const float*)d_in[1];
  const int*   C_den    = (const int*)d_in[2];
  const float* C_syn_e  = (const float*)d_in[3];
  const float* C_syn_i  = (const float*)d_in[4];
  const float* cos_b    = (const float*)d_in[5];
  const float* Tau_e    = (const float*)d_in[6];
  const float* Tau_i    = (const float*)d_in[7];
  const float* W_e      = (const float*)d_in[8];
  const float* W_i      = (const float*)d_in[9];
  const float* D_e      = (const float*)d_in[10];
  const float* D_i      = (const float*)d_in[11];
  const float* W_sub    = (const float*)d_in[12];
  const float* W_hist   = (const float*)d_in[13];
  const float* Theta    = (const float*)d_in[14];
  float* out = (float*)d_out;

  float* wsf      = (float*)d_ws;
  float* ws_ek    = wsf;
  float* ws_ik    = wsf + 3200;
  float* ws_hist  = wsf + 6400;
  float* ws_ewsub = wsf + 6600;
  float* ws_we    = wsf + 6616;
  float* ws_wi    = wsf + 8616;
  float* synE     = wsf + 16384;
  float* synI     = wsf + 336384;
  float* negd     = wsf + 656384;
  int*   ws_me    = (int*)(wsf + 676384);
  int*   ws_mi    = (int*)(wsf + 678384);
  int*   ws_cmask = (int*)(wsf + 678884);

  k_prep<<<dim3(1), dim3(256), 0, stream>>>(
      C_syn_e, C_syn_i, cos_b, Tau_e, Tau_i, W_e, W_i, D_e, D_i, W_sub, W_hist,
      C_den, ws_ek, ws_ik, ws_hist, ws_ewsub, ws_we, ws_wi, ws_me, ws_mi,
      ws_cmask, out + T_DATA);

  k_agg<<<dim3(1250), dim3(256), 0, stream>>>(
      (const float4*)S_e, (const float4*)S_i, ws_me, ws_we, ws_mi, ws_wi,
      synE, synI);

  k_filt<<<dim3(NBLK), dim3(64), 0, stream>>>(
      synE, synI, ws_ek, ws_ik, Theta, ws_ewsub, ws_cmask, negd);

  k_scan<<<dim3(1), dim3(256), 0, stream>>>(ws_hist, negd, out);
}

// Round 12
// 786.522 us; speedup vs baseline: 1.7744x; 1.7744x over previous
//
#include <hip/hip_runtime.h>
#include <math.h>
#include <stdint.h>

#define T_DATA 20000
#define E_NO   2000
#define I_NO   500
#define SUB    16
#define TNO    200
#define NBLK   313   // ceil(20000/64)

// ---------------- workspace layout (float offsets) ----------------
// 0       ek[3200]   (s*200+t)
// 3200    ik[3200]
// 6400    hist[200]
// 6600    ewsub[16]
// 6616    we[2000]
// 8616    wi[500]
// 16384   synE[20000*16]
// 336384  synI[20000*16]
// 656384  negd[20000]
// 676384  me[2000] (int)
// 678384  mi[500]  (int)
// 678884  cmask[16](int)

// ---------------------------------------------------------------------------
// K1: per-subunit kernels, hist kernel, synapse->subunit maps, tree masks.
// ---------------------------------------------------------------------------
__global__ __launch_bounds__(256) void k_prep(
    const float* __restrict__ Ce, const float* __restrict__ Ci,
    const float* __restrict__ cosb,
    const float* __restrict__ TauE, const float* __restrict__ TauI,
    const float* __restrict__ We,  const float* __restrict__ Wi,
    const float* __restrict__ De,  const float* __restrict__ Di,
    const float* __restrict__ Wsub, const float* __restrict__ Whist,
    const int* __restrict__ Cden,
    float* __restrict__ ws_ek, float* __restrict__ ws_ik,
    float* __restrict__ ws_hist, float* __restrict__ ws_ewsub,
    float* __restrict__ ws_we, float* __restrict__ ws_wi,
    int* __restrict__ ws_me, int* __restrict__ ws_mi, int* __restrict__ ws_cmask,
    float* __restrict__ out_filt) {
  int tid = threadIdx.x;
  for (int idx = tid; idx < SUB * TNO; idx += 256) {
    int s = idx / TNO;
    float tf = (float)(idx % TNO);
    float te  = fmaxf(tf - expf(De[s]), 0.f);
    float tte = te / expf(TauE[s]);
    float ekv = tte * expf(-tte) * expf(We[s]);
    float ti_ = fmaxf(tf - expf(Di[s]), 0.f);
    float tti = ti_ / expf(TauI[s]);
    float ikv = -(tti * expf(-tti) * expf(Wi[s]));
    ws_ek[idx] = ekv;
    ws_ik[idx] = ikv;
    out_filt[idx] = ekv;            // rows 0..15
    out_filt[3200 + idx] = ikv;     // rows 16..31
  }
  for (int t = tid; t < TNO; t += 256) {
    float h = 0.f;
    for (int b = 0; b < 16; ++b) h = fmaf(Whist[b], cosb[b * TNO + t], h);
    ws_hist[t] = h;
    out_filt[6400 + t] = h;         // row 32 (unflipped)
  }
  for (int e = tid; e < E_NO; e += 256) {
    int m = 0; float w = 0.f;
    for (int s = 0; s < SUB; ++s) {
      float v = Ce[s * E_NO + e];
      if (w == 0.f && v != 0.f) { m = s; w = v; }
    }
    ws_me[e] = m; ws_we[e] = w;
  }
  for (int e = tid; e < I_NO; e += 256) {
    int m = 0; float w = 0.f;
    for (int s = 0; s < SUB; ++s) {
      float v = Ci[s * I_NO + e];
      if (w == 0.f && v != 0.f) { m = s; w = v; }
    }
    ws_mi[e] = m; ws_wi[e] = w;
  }
  if (tid < SUB) {
    ws_ewsub[tid] = expf(Wsub[tid]);
    int msk = 0;
    for (int j = 0; j < SUB; ++j)
      if (Cden[tid * SUB + j] == 1) msk |= (1 << j);
    ws_cmask[tid] = msk;
  }
}

// ---------------------------------------------------------------------------
// K2: synapse aggregation -> synE/synI [20000][16]. Deterministic.
// ---------------------------------------------------------------------------
__global__ __launch_bounds__(256) void k_agg(
    const float4* __restrict__ Se4, const float4* __restrict__ Si4,
    const int* __restrict__ me, const float* __restrict__ we,
    const int* __restrict__ mi, const float* __restrict__ wi,
    float* __restrict__ synE, float* __restrict__ synI) {
  __shared__ float bins[4][64][33];
  int tid = threadIdx.x, wid = tid >> 6, l = tid & 63;
  int gw = blockIdx.x * 4 + wid;
  for (int r = 0; r < 4; ++r) {
    int t = gw * 4 + r;
#pragma unroll
    for (int s = 0; s < 32; ++s) bins[wid][l][s] = 0.f;
    for (int i = 0; i < 8; ++i) {
      int idx = i * 64 + l;
      if (idx < 500) {
        float4 v = Se4[(size_t)t * 500 + idx];
        int e0 = idx * 4;
        if (v.x != 0.f) bins[wid][l][me[e0 + 0]] += v.x * we[e0 + 0];
        if (v.y != 0.f) bins[wid][l][me[e0 + 1]] += v.y * we[e0 + 1];
        if (v.z != 0.f) bins[wid][l][me[e0 + 2]] += v.z * we[e0 + 2];
        if (v.w != 0.f) bins[wid][l][me[e0 + 3]] += v.w * we[e0 + 3];
      }
    }
    for (int i = 0; i < 2; ++i) {
      int idx = i * 64 + l;
      if (idx < 125) {
        float4 v = Si4[(size_t)t * 125 + idx];
        int e0 = idx * 4;
        if (v.x != 0.f) bins[wid][l][16 + mi[e0 + 0]] += v.x * wi[e0 + 0];
        if (v.y != 0.f) bins[wid][l][16 + mi[e0 + 1]] += v.y * wi[e0 + 1];
        if (v.z != 0.f) bins[wid][l][16 + mi[e0 + 2]] += v.z * wi[e0 + 2];
        if (v.w != 0.f) bins[wid][l][16 + mi[e0 + 3]] += v.w * wi[e0 + 3];
      }
    }
    __syncthreads();
    if (l < 32) {
      float a = 0.f;
      for (int k = 0; k < 64; ++k) a += bins[wid][k][l];
      if (l < 16) synE[(size_t)t * 16 + l] = a;
      else        synI[(size_t)t * 16 + (l - 16)] = a;
    }
    __syncthreads();
  }
}

// ---------------------------------------------------------------------------
// K3: causal filtering + dendritic tree -> negd[t] = -drive[t].
// ---------------------------------------------------------------------------
__global__ __launch_bounds__(64) void k_filt(
    const float* __restrict__ synE, const float* __restrict__ synI,
    const float* __restrict__ ek_ws, const float* __restrict__ ik_ws,
    const float* __restrict__ theta, const float* __restrict__ ewsub,
    const int* __restrict__ cmask,
    float* __restrict__ negd) {
  __shared__ float sE[264 * 17];
  __shared__ float sI[264 * 17];
  __shared__ float ekl[TNO * 16];
  __shared__ float ikl[TNO * 16];
  int l = threadIdx.x;
  int t0 = blockIdx.x * 64;
  for (int idx = l; idx < 264 * 16; idx += 64) {
    int row = idx >> 4, s = idx & 15;
    int g = t0 - 200 + row;
    bool ok = (g >= 0) && (g < T_DATA);
    sE[row * 17 + s] = ok ? synE[(size_t)g * 16 + s] : 0.f;
    sI[row * 17 + s] = ok ? synI[(size_t)g * 16 + s] : 0.f;
  }
  for (int idx = l; idx < SUB * TNO; idx += 64) {
    int s = idx / TNO, j = idx % TNO;
    ekl[j * 16 + s] = ek_ws[idx];
    ikl[j * 16 + s] = ik_ws[idx];
  }
  __syncthreads();
  int t = t0 + l;
  float acc[16];
#pragma unroll
  for (int s = 0; s < 16; ++s) acc[s] = 0.f;
  for (int j = 0; j < TNO; ++j) {
    int base = (l + 199 - j) * 17;
    int kb = j * 16;
#pragma unroll
    for (int s = 0; s < 16; ++s)
      acc[s] = fmaf(ekl[kb + s], sE[base + s], fmaf(ikl[kb + s], sI[base + s], acc[s]));
  }
  float th[16], ew[16]; int cm[16];
#pragma unroll
  for (int s = 0; s < 16; ++s) { th[s] = theta[s]; ew[s] = ewsub[s]; cm[s] = cmask[s]; }
  float val[16];
#pragma unroll
  for (int s = 0; s < 16; ++s) val[s] = 0.f;
#pragma unroll
  for (int sidx = 15; sidx >= 1; --sidx) {
    float sum = acc[sidx] + th[sidx];
#pragma unroll
    for (int j = 0; j < 16; ++j)
      if ((cm[sidx] >> j) & 1) sum += val[j] * ew[j];
    val[sidx] = tanhf(sum);
  }
  float drive = acc[0] + th[0];
#pragma unroll
  for (int j = 0; j < 16; ++j)
    if ((cm[0] >> j) & 1) drive += val[j] * ew[j];
  if (t < T_DATA) negd[t] = -drive;
}

// ---------------------------------------------------------------------------
// K4: sequential spike scan. 1 workgroup, 4 waves (one per SIMD).
// ROUND 12: EXACT revert to the R8 structure (measured 610us k_scan — best).
// R9/R10/R11 all regressed: monolithic asm, cndmask tail, and C-ternary
// 4-step tree each cost more than the VALU->SALU->VALU round trip they
// tried to save. R8's idiom: per pair (i,i+1), two v_cmp in one small asm
// block, C scalar select (s_cselect), cvt+fma tail.
// ---------------------------------------------------------------------------
__global__
__attribute__((amdgpu_flat_work_group_size(256, 256), amdgpu_waves_per_eu(1, 1)))
void k_scan(
    const float* __restrict__ hist, const float* __restrict__ negd,
    float* __restrict__ out_spk) {
  __shared__ float hpad[328];        // [0..63]=0, [64..263]=h[0..199], [264..327]=0
  __shared__ unsigned long long mring[8];  // per-block spike masks, slot n&7
  __shared__ float deepb[2][3][64];  // parity double-buffered deep partials
  int tid = threadIdx.x, wid = tid >> 6, l = tid & 63;
  for (int i = tid; i < 328; i += 256) hpad[i] = (i >= 64 && i < 264) ? hist[i - 64] : 0.f;
  if (tid < 8) mring[tid] = 0ull;
  for (int i = tid; i < 2 * 3 * 64; i += 256) (&deepb[0][0][0])[i] = 0.f;
  __syncthreads();

  // wave0: h(j) = hpad[l + j].  chain step i adds h(63-i); boundary tap i
  // adds h(127-i).
  float h0=0,h1=0,h2=0,h3=0,h4=0,h5=0,h6=0,h7=0,h8=0,h9=0,h10=0,h11=0,h12=0,h13=0,h14=0,h15=0,
        h16=0,h17=0,h18=0,h19=0,h20=0,h21=0,h22=0,h23=0,h24=0,h25=0,h26=0,h27=0,h28=0,h29=0,h30=0,h31=0,
        h32=0,h33=0,h34=0,h35=0,h36=0,h37=0,h38=0,h39=0,h40=0,h41=0,h42=0,h43=0,h44=0,h45=0,h46=0,h47=0,
        h48=0,h49=0,h50=0,h51=0,h52=0,h53=0,h54=0,h55=0,h56=0,h57=0,h58=0,h59=0,h60=0,h61=0,h62=0,h63=0,
        h64=0,h65=0,h66=0,h67=0,h68=0,h69=0,h70=0,h71=0,h72=0,h73=0,h74=0,h75=0,h76=0,h77=0,h78=0,h79=0,
        h80=0,h81=0,h82=0,h83=0,h84=0,h85=0,h86=0,h87=0,h88=0,h89=0,h90=0,h91=0,h92=0,h93=0,h94=0,h95=0,
        h96=0,h97=0,h98=0,h99=0,h100=0,h101=0,h102=0,h103=0,h104=0,h105=0,h106=0,h107=0,h108=0,h109=0,h110=0,h111=0,
        h112=0,h113=0,h114=0,h115=0,h116=0,h117=0,h118=0,h119=0,h120=0,h121=0,h122=0,h123=0,h124=0,h125=0,h126=0,h127=0;
  // deep-wave tap registers: hd(j) = hpad[dbase + l + j]
  float hd0=0,hd1=0,hd2=0,hd3=0,hd4=0,hd5=0,hd6=0,hd7=0,hd8=0,hd9=0,hd10=0,hd11=0,hd12=0,hd13=0,hd14=0,hd15=0,
        hd16=0,hd17=0,hd18=0,hd19=0,hd20=0,hd21=0,hd22=0,hd23=0,hd24=0,hd25=0,hd26=0,hd27=0,hd28=0,hd29=0,hd30=0,hd31=0,
        hd32=0,hd33=0,hd34=0,hd35=0,hd36=0,hd37=0,hd38=0,hd39=0,hd40=0,hd41=0,hd42=0,hd43=0,hd44=0,hd45=0;
  if (wid == 0) {
#define LD(j) h##j = hpad[l + j];
    LD(0)LD(1)LD(2)LD(3)LD(4)LD(5)LD(6)LD(7)LD(8)LD(9)LD(10)LD(11)LD(12)LD(13)LD(14)LD(15)
    LD(16)LD(17)LD(18)LD(19)LD(20)LD(21)LD(22)LD(23)LD(24)LD(25)LD(26)LD(27)LD(28)LD(29)LD(30)LD(31)
    LD(32)LD(33)LD(34)LD(35)LD(36)LD(37)LD(38)LD(39)LD(40)LD(41)LD(42)LD(43)LD(44)LD(45)LD(46)LD(47)
    LD(48)LD(49)LD(50)LD(51)LD(52)LD(53)LD(54)LD(55)LD(56)LD(57)LD(58)LD(59)LD(60)LD(61)LD(62)LD(63)
    LD(64)LD(65)LD(66)LD(67)LD(68)LD(69)LD(70)LD(71)LD(72)LD(73)LD(74)LD(75)LD(76)LD(77)LD(78)LD(79)
    LD(80)LD(81)LD(82)LD(83)LD(84)LD(85)LD(86)LD(87)LD(88)LD(89)LD(90)LD(91)LD(92)LD(93)LD(94)LD(95)
    LD(96)LD(97)LD(98)LD(99)LD(100)LD(101)LD(102)LD(103)LD(104)LD(105)LD(106)LD(107)LD(108)LD(109)LD(110)LD(111)
    LD(112)LD(113)LD(114)LD(115)LD(116)LD(117)LD(118)LD(119)LD(120)LD(121)LD(122)LD(123)LD(124)LD(125)LD(126)LD(127)
#undef LD
  } else {
    int dbase = (wid == 2) ? 174 : (wid == 3) ? 219 : 128;
#define LHD(j) hd##j = hpad[dbase + l + j];
    LHD(0)LHD(1)LHD(2)LHD(3)LHD(4)LHD(5)LHD(6)LHD(7)LHD(8)LHD(9)LHD(10)LHD(11)LHD(12)LHD(13)LHD(14)LHD(15)
    LHD(16)LHD(17)LHD(18)LHD(19)LHD(20)LHD(21)LHD(22)LHD(23)LHD(24)LHD(25)LHD(26)LHD(27)LHD(28)LHD(29)LHD(30)LHD(31)
    LHD(32)LHD(33)LHD(34)LHD(35)LHD(36)LHD(37)LHD(38)LHD(39)LHD(40)LHD(41)LHD(42)LHD(43)LHD(44)LHD(45)
#undef LHD
  }

  unsigned long long mask_prev = 0ull;
  float ndv = (wid == 0) ? negd[l] : 0.f;

  for (int n = 0; n < NBLK; ++n) {
    int t0 = n * 64;
    if (wid == 0) {
      int tn = t0 + 64 + l;
      float ndnext = (tn < T_DATA) ? negd[tn] : INFINITY;
      int par = n & 1;
      float X = deepb[par][0][l] + deepb[par][1][l] + deepb[par][2][l];
      // boundary conv: prev-block bit i adds h(127-i) — pure register math
      {
        float a0 = 0.f, a1 = 0.f, a2 = 0.f, a3 = 0.f;
#define BD(i, hv, acc) acc = fmaf((float)((mask_prev >> (i)) & 1ull), hv, acc);
        BD(0,h127,a0)BD(1,h126,a1)BD(2,h125,a2)BD(3,h124,a3)
        BD(4,h123,a0)BD(5,h122,a1)BD(6,h121,a2)BD(7,h120,a3)
        BD(8,h119,a0)BD(9,h118,a1)BD(10,h117,a2)BD(11,h116,a3)
        BD(12,h115,a0)BD(13,h114,a1)BD(14,h113,a2)BD(15,h112,a3)
        BD(16,h111,a0)BD(17,h110,a1)BD(18,h109,a2)BD(19,h108,a3)
        BD(20,h107,a0)BD(21,h106,a1)BD(22,h105,a2)BD(23,h104,a3)
        BD(24,h103,a0)BD(25,h102,a1)BD(26,h101,a2)BD(27,h100,a3)
        BD(28,h99,a0)BD(29,h98,a1)BD(30,h97,a2)BD(31,h96,a3)
        BD(32,h95,a0)BD(33,h94,a1)BD(34,h93,a2)BD(35,h92,a3)
        BD(36,h91,a0)BD(37,h90,a1)BD(38,h89,a2)BD(39,h88,a3)
        BD(40,h87,a0)BD(41,h86,a1)BD(42,h85,a2)BD(43,h84,a3)
        BD(44,h83,a0)BD(45,h82,a1)BD(46,h81,a2)BD(47,h80,a3)
        BD(48,h79,a0)BD(49,h78,a1)BD(50,h77,a2)BD(51,h76,a3)
        BD(52,h75,a0)BD(53,h74,a1)BD(54,h73,a2)BD(55,h72,a3)
        BD(56,h71,a0)BD(57,h70,a1)BD(58,h69,a2)BD(59,h68,a3)
        BD(60,h67,a0)BD(61,h66,a1)BD(62,h65,a2)BD(63,h64,a3)
#undef BD
        X += (a0 + a1) + (a2 + a3);
      }
      // 2-step lookahead chain: 32 pairs cover steps 0..63 (R8 idiom)
      unsigned long long msk = 0ull;
#define CH2(i, hvA, hvB) { \
      float Xa = X + hvA; \
      unsigned long long bm0, bm1; \
      asm("v_cmp_gt_f32 %0, %2, %4\n\t" \
          "v_cmp_gt_f32 %1, %3, %4" \
          : "=s"(bm0), "=s"(bm1) : "v"(X), "v"(Xa), "v"(ndv)); \
      unsigned s0b = (unsigned)(bm0 >> (i)) & 1u; \
      unsigned long long bmx = s0b ? bm1 : bm0; \
      unsigned s1b = (unsigned)(bmx >> ((i) + 1)) & 1u; \
      float s0f = (float)s0b, s1f = (float)s1b; \
      X = fmaf(s0f, hvA, X); \
      X = fmaf(s1f, hvB, X); \
      msk |= ((unsigned long long)s0b << (i)) | ((unsigned long long)s1b << ((i) + 1)); }
      CH2(0,h63,h62)  CH2(2,h61,h60)  CH2(4,h59,h58)  CH2(6,h57,h56)
      CH2(8,h55,h54)  CH2(10,h53,h52) CH2(12,h51,h50) CH2(14,h49,h48)
      CH2(16,h47,h46) CH2(18,h45,h44) CH2(20,h43,h42) CH2(22,h41,h40)
      CH2(24,h39,h38) CH2(26,h37,h36) CH2(28,h35,h34) CH2(30,h33,h32)
      CH2(32,h31,h30) CH2(34,h29,h28) CH2(36,h27,h26) CH2(38,h25,h24)
      CH2(40,h23,h22) CH2(42,h21,h20) CH2(44,h19,h18) CH2(46,h17,h16)
      CH2(48,h15,h14) CH2(50,h13,h12) CH2(52,h11,h10) CH2(54,h9,h8)
      CH2(56,h7,h6)   CH2(58,h5,h4)   CH2(60,h3,h2)   CH2(62,h1,h0)
#undef CH2
      // publish: spike output + block mask
      float myspk = (float)((msk >> l) & 1ull);
      int t = t0 + l;
      if (t < T_DATA) out_spk[t] = myspk;
      if (l == 0) mring[n & 7] = msk;
      mask_prev = msk;
      ndv = ndnext;
    } else {
      // deep feedback for block n+1 from spike bitmasks of blocks n-1..n-3.
      unsigned long long M1 = mring[(n + 7) & 7];
      unsigned long long M2 = mring[(n + 6) & 7];
      unsigned long long M3 = mring[(n + 5) & 7];
      M1 = ((unsigned long long)__builtin_amdgcn_readfirstlane((unsigned)(M1 >> 32)) << 32)
           | (unsigned)__builtin_amdgcn_readfirstlane((unsigned)M1);
      M2 = ((unsigned long long)__builtin_amdgcn_readfirstlane((unsigned)(M2 >> 32)) << 32)
           | (unsigned)__builtin_amdgcn_readfirstlane((unsigned)M2);
      M3 = ((unsigned long long)__builtin_amdgcn_readfirstlane((unsigned)(M3 >> 32)) << 32)
           | (unsigned)__builtin_amdgcn_readfirstlane((unsigned)M3);
      float a0 = 0.f, a1 = 0.f, a2 = 0.f, a3 = 0.f;
#define DT(j, M, b, acc) acc = fmaf((float)(((M) >> (b)) & 1ull), hd##j, acc);
      if (wid == 1) {
        DT(0,M1,63,a0)DT(1,M1,62,a1)DT(2,M1,61,a2)DT(3,M1,60,a3)
        DT(4,M1,59,a0)DT(5,M1,58,a1)DT(6,M1,57,a2)DT(7,M1,56,a3)
        DT(8,M1,55,a0)DT(9,M1,54,a1)DT(10,M1,53,a2)DT(11,M1,52,a3)
        DT(12,M1,51,a0)DT(13,M1,50,a1)DT(14,M1,49,a2)DT(15,M1,48,a3)
        DT(16,M1,47,a0)DT(17,M1,46,a1)DT(18,M1,45,a2)DT(19,M1,44,a3)
        DT(20,M1,43,a0)DT(21,M1,42,a1)DT(22,M1,41,a2)DT(23,M1,40,a3)
        DT(24,M1,39,a0)DT(25,M1,38,a1)DT(26,M1,37,a2)DT(27,M1,36,a3)
        DT(28,M1,35,a0)DT(29,M1,34,a1)DT(30,M1,33,a2)DT(31,M1,32,a3)
        DT(32,M1,31,a0)DT(33,M1,30,a1)DT(34,M1,29,a2)DT(35,M1,28,a3)
        DT(36,M1,27,a0)DT(37,M1,26,a1)DT(38,M1,25,a2)DT(39,M1,24,a3)
        DT(40,M1,23,a0)DT(41,M1,22,a1)DT(42,M1,21,a2)DT(43,M1,20,a3)
        DT(44,M1,19,a0)DT(45,M1,18,a1)
      } else if (wid == 2) {
        DT(0,M1,17,a0)DT(1,M1,16,a1)DT(2,M1,15,a2)DT(3,M1,14,a3)
        DT(4,M1,13,a0)DT(5,M1,12,a1)DT(6,M1,11,a2)DT(7,M1,10,a3)
        DT(8,M1,9,a0)DT(9,M1,8,a1)DT(10,M1,7,a2)DT(11,M1,6,a3)
        DT(12,M1,5,a0)DT(13,M1,4,a1)DT(14,M1,3,a2)DT(15,M1,2,a3)
        DT(16,M1,1,a0)DT(17,M1,0,a1)
        DT(18,M2,63,a2)DT(19,M2,62,a3)
        DT(20,M2,61,a0)DT(21,M2,60,a1)DT(22,M2,59,a2)DT(23,M2,58,a3)
        DT(24,M2,57,a0)DT(25,M2,56,a1)DT(26,M2,55,a2)DT(27,M2,54,a3)
        DT(28,M2,53,a0)DT(29,M2,52,a1)DT(30,M2,51,a2)DT(31,M2,50,a3)
        DT(32,M2,49,a0)DT(33,M2,48,a1)DT(34,M2,47,a2)DT(35,M2,46,a3)
        DT(36,M2,45,a0)DT(37,M2,44,a1)DT(38,M2,43,a2)DT(39,M2,42,a3)
        DT(40,M2,41,a0)DT(41,M2,40,a1)DT(42,M2,39,a2)DT(43,M2,38,a3)
        DT(44,M2,37,a0)
      } else {
        DT(0,M2,36,a0)DT(1,M2,35,a1)DT(2,M2,34,a2)DT(3,M2,33,a3)
        DT(4,M2,32,a0)DT(5,M2,31,a1)DT(6,M2,30,a2)DT(7,M2,29,a3)
        DT(8,M2,28,a0)DT(9,M2,27,a1)DT(10,M2,26,a2)DT(11,M2,25,a3)
        DT(12,M2,24,a0)DT(13,M2,23,a1)DT(14,M2,22,a2)DT(15,M2,21,a3)
        DT(16,M2,20,a0)DT(17,M2,19,a1)DT(18,M2,18,a2)DT(19,M2,17,a3)
        DT(20,M2,16,a0)DT(21,M2,15,a1)DT(22,M2,14,a2)DT(23,M2,13,a3)
        DT(24,M2,12,a0)DT(25,M2,11,a1)DT(26,M2,10,a2)DT(27,M2,9,a3)
        DT(28,M2,8,a0)DT(29,M2,7,a1)DT(30,M2,6,a2)DT(31,M2,5,a3)
        DT(32,M2,4,a0)DT(33,M2,3,a1)DT(34,M2,2,a2)DT(35,M2,1,a3)
        DT(36,M2,0,a0)
        DT(37,M3,63,a1)DT(38,M3,62,a2)DT(39,M3,61,a3)
        DT(40,M3,60,a0)DT(41,M3,59,a1)DT(42,M3,58,a2)DT(43,M3,57,a3)
        DT(44,M3,56,a0)
      }
#undef DT
      deepb[(n + 1) & 1][wid - 1][l] = (a0 + a1) + (a2 + a3);
    }
    __syncthreads();
  }
}

// ---------------------------------------------------------------------------
extern "C" void kernel_launch(void* const* d_in, const int* in_sizes, int n_in,
                              void* d_out, int out_size, void* d_ws, size_t ws_size,
                              hipStream_t stream) {
  const float* S_e      = (const float*)d_in[0];
  const float* S_i      = (const float*)d_in[1];
  const int*   C_den    = (const int*)d_in[2];
  const float* C_syn_e  = (const float*)d_in[3];
  const float* C_syn_i  = (const float*)d_in[4];
  const float* cos_b    = (const float*)d_in[5];
  const float* Tau_e    = (const float*)d_in[6];
  const float* Tau_i    = (const float*)d_in[7];
  const float* W_e      = (const float*)d_in[8];
  const float* W_i      = (const float*)d_in[9];
  const float* D_e      = (const float*)d_in[10];
  const float* D_i      = (const float*)d_in[11];
  const float* W_sub    = (const float*)d_in[12];
  const float* W_hist   = (const float*)d_in[13];
  const float* Theta    = (const float*)d_in[14];
  float* out = (float*)d_out;

  float* wsf      = (float*)d_ws;
  float* ws_ek    = wsf;
  float* ws_ik    = wsf + 3200;
  float* ws_hist  = wsf + 6400;
  float* ws_ewsub = wsf + 6600;
  float* ws_we    = wsf + 6616;
  float* ws_wi    = wsf + 8616;
  float* synE     = wsf + 16384;
  float* synI     = wsf + 336384;
  float* negd     = wsf + 656384;
  int*   ws_me    = (int*)(wsf + 676384);
  int*   ws_mi    = (int*)(wsf + 678384);
  int*   ws_cmask = (int*)(wsf + 678884);

  k_prep<<<dim3(1), dim3(256), 0, stream>>>(
      C_syn_e, C_syn_i, cos_b, Tau_e, Tau_i, W_e, W_i, D_e, D_i, W_sub, W_hist,
      C_den, ws_ek, ws_ik, ws_hist, ws_ewsub, ws_we, ws_wi, ws_me, ws_mi,
      ws_cmask, out + T_DATA);

  k_agg<<<dim3(1250), dim3(256), 0, stream>>>(
      (const float4*)S_e, (const float4*)S_i, ws_me, ws_we, ws_mi, ws_wi,
      synE, synI);

  k_filt<<<dim3(NBLK), dim3(64), 0, stream>>>(
      synE, synI, ws_ek, ws_ik, Theta, ws_ewsub, ws_cmask, negd);

  k_scan<<<dim3(1), dim3(256), 0, stream>>>(ws_hist, negd, out);
}

// Round 13
// 699.320 us; speedup vs baseline: 1.9957x; 1.1247x over previous
//
#include <hip/hip_runtime.h>
#include <math.h>
#include <stdint.h>

#define T_DATA 20000
#define E_NO   2000
#define I_NO   500
#define SUB    16
#define TNO    200
#define NBLK   313   // ceil(20000/64)

// ---------------- workspace layout (float offsets) ----------------
// 0       ek[3200]   (s*200+t)
// 3200    ik[3200]
// 6400    hist[200]
// 6600    ewsub[16]
// 6616    we[2000]
// 8616    wi[500]
// 16384   synE[20000*16]
// 336384  synI[20000*16]
// 656384  negd[20000]
// 676384  me[2000] (int)
// 678384  mi[500]  (int)
// 678884  cmask[16](int)

// ---------------------------------------------------------------------------
// K1: per-subunit kernels, hist kernel, synapse->subunit maps, tree masks.
// ---------------------------------------------------------------------------
__global__ __launch_bounds__(256) void k_prep(
    const float* __restrict__ Ce, const float* __restrict__ Ci,
    const float* __restrict__ cosb,
    const float* __restrict__ TauE, const float* __restrict__ TauI,
    const float* __restrict__ We,  const float* __restrict__ Wi,
    const float* __restrict__ De,  const float* __restrict__ Di,
    const float* __restrict__ Wsub, const float* __restrict__ Whist,
    const int* __restrict__ Cden,
    float* __restrict__ ws_ek, float* __restrict__ ws_ik,
    float* __restrict__ ws_hist, float* __restrict__ ws_ewsub,
    float* __restrict__ ws_we, float* __restrict__ ws_wi,
    int* __restrict__ ws_me, int* __restrict__ ws_mi, int* __restrict__ ws_cmask,
    float* __restrict__ out_filt) {
  int tid = threadIdx.x;
  for (int idx = tid; idx < SUB * TNO; idx += 256) {
    int s = idx / TNO;
    float tf = (float)(idx % TNO);
    float te  = fmaxf(tf - expf(De[s]), 0.f);
    float tte = te / expf(TauE[s]);
    float ekv = tte * expf(-tte) * expf(We[s]);
    float ti_ = fmaxf(tf - expf(Di[s]), 0.f);
    float tti = ti_ / expf(TauI[s]);
    float ikv = -(tti * expf(-tti) * expf(Wi[s]));
    ws_ek[idx] = ekv;
    ws_ik[idx] = ikv;
    out_filt[idx] = ekv;            // rows 0..15
    out_filt[3200 + idx] = ikv;     // rows 16..31
  }
  for (int t = tid; t < TNO; t += 256) {
    float h = 0.f;
    for (int b = 0; b < 16; ++b) h = fmaf(Whist[b], cosb[b * TNO + t], h);
    ws_hist[t] = h;
    out_filt[6400 + t] = h;         // row 32 (unflipped)
  }
  for (int e = tid; e < E_NO; e += 256) {
    int m = 0; float w = 0.f;
    for (int s = 0; s < SUB; ++s) {
      float v = Ce[s * E_NO + e];
      if (w == 0.f && v != 0.f) { m = s; w = v; }
    }
    ws_me[e] = m; ws_we[e] = w;
  }
  for (int e = tid; e < I_NO; e += 256) {
    int m = 0; float w = 0.f;
    for (int s = 0; s < SUB; ++s) {
      float v = Ci[s * I_NO + e];
      if (w == 0.f && v != 0.f) { m = s; w = v; }
    }
    ws_mi[e] = m; ws_wi[e] = w;
  }
  if (tid < SUB) {
    ws_ewsub[tid] = expf(Wsub[tid]);
    int msk = 0;
    for (int j = 0; j < SUB; ++j)
      if (Cden[tid * SUB + j] == 1) msk |= (1 << j);
    ws_cmask[tid] = msk;
  }
}

// ---------------------------------------------------------------------------
// K2: synapse aggregation -> synE/synI [20000][16]. Deterministic.
// ---------------------------------------------------------------------------
__global__ __launch_bounds__(256) void k_agg(
    const float4* __restrict__ Se4, const float4* __restrict__ Si4,
    const int* __restrict__ me, const float* __restrict__ we,
    const int* __restrict__ mi, const float* __restrict__ wi,
    float* __restrict__ synE, float* __restrict__ synI) {
  __shared__ float bins[4][64][33];
  int tid = threadIdx.x, wid = tid >> 6, l = tid & 63;
  int gw = blockIdx.x * 4 + wid;
  for (int r = 0; r < 4; ++r) {
    int t = gw * 4 + r;
#pragma unroll
    for (int s = 0; s < 32; ++s) bins[wid][l][s] = 0.f;
    for (int i = 0; i < 8; ++i) {
      int idx = i * 64 + l;
      if (idx < 500) {
        float4 v = Se4[(size_t)t * 500 + idx];
        int e0 = idx * 4;
        if (v.x != 0.f) bins[wid][l][me[e0 + 0]] += v.x * we[e0 + 0];
        if (v.y != 0.f) bins[wid][l][me[e0 + 1]] += v.y * we[e0 + 1];
        if (v.z != 0.f) bins[wid][l][me[e0 + 2]] += v.z * we[e0 + 2];
        if (v.w != 0.f) bins[wid][l][me[e0 + 3]] += v.w * we[e0 + 3];
      }
    }
    for (int i = 0; i < 2; ++i) {
      int idx = i * 64 + l;
      if (idx < 125) {
        float4 v = Si4[(size_t)t * 125 + idx];
        int e0 = idx * 4;
        if (v.x != 0.f) bins[wid][l][16 + mi[e0 + 0]] += v.x * wi[e0 + 0];
        if (v.y != 0.f) bins[wid][l][16 + mi[e0 + 1]] += v.y * wi[e0 + 1];
        if (v.z != 0.f) bins[wid][l][16 + mi[e0 + 2]] += v.z * wi[e0 + 2];
        if (v.w != 0.f) bins[wid][l][16 + mi[e0 + 3]] += v.w * wi[e0 + 3];
      }
    }
    __syncthreads();
    if (l < 32) {
      float a = 0.f;
      for (int k = 0; k < 64; ++k) a += bins[wid][k][l];
      if (l < 16) synE[(size_t)t * 16 + l] = a;
      else        synI[(size_t)t * 16 + (l - 16)] = a;
    }
    __syncthreads();
  }
}

// ---------------------------------------------------------------------------
// K3: causal filtering + dendritic tree -> negd[t] = -drive[t].
// ---------------------------------------------------------------------------
__global__ __launch_bounds__(64) void k_filt(
    const float* __restrict__ synE, const float* __restrict__ synI,
    const float* __restrict__ ek_ws, const float* __restrict__ ik_ws,
    const float* __restrict__ theta, const float* __restrict__ ewsub,
    const int* __restrict__ cmask,
    float* __restrict__ negd) {
  __shared__ float sE[264 * 17];
  __shared__ float sI[264 * 17];
  __shared__ float ekl[TNO * 16];
  __shared__ float ikl[TNO * 16];
  int l = threadIdx.x;
  int t0 = blockIdx.x * 64;
  for (int idx = l; idx < 264 * 16; idx += 64) {
    int row = idx >> 4, s = idx & 15;
    int g = t0 - 200 + row;
    bool ok = (g >= 0) && (g < T_DATA);
    sE[row * 17 + s] = ok ? synE[(size_t)g * 16 + s] : 0.f;
    sI[row * 17 + s] = ok ? synI[(size_t)g * 16 + s] : 0.f;
  }
  for (int idx = l; idx < SUB * TNO; idx += 64) {
    int s = idx / TNO, j = idx % TNO;
    ekl[j * 16 + s] = ek_ws[idx];
    ikl[j * 16 + s] = ik_ws[idx];
  }
  __syncthreads();
  int t = t0 + l;
  float acc[16];
#pragma unroll
  for (int s = 0; s < 16; ++s) acc[s] = 0.f;
  for (int j = 0; j < TNO; ++j) {
    int base = (l + 199 - j) * 17;
    int kb = j * 16;
#pragma unroll
    for (int s = 0; s < 16; ++s)
      acc[s] = fmaf(ekl[kb + s], sE[base + s], fmaf(ikl[kb + s], sI[base + s], acc[s]));
  }
  float th[16], ew[16]; int cm[16];
#pragma unroll
  for (int s = 0; s < 16; ++s) { th[s] = theta[s]; ew[s] = ewsub[s]; cm[s] = cmask[s]; }
  float val[16];
#pragma unroll
  for (int s = 0; s < 16; ++s) val[s] = 0.f;
#pragma unroll
  for (int sidx = 15; sidx >= 1; --sidx) {
    float sum = acc[sidx] + th[sidx];
#pragma unroll
    for (int j = 0; j < 16; ++j)
      if ((cm[sidx] >> j) & 1) sum += val[j] * ew[j];
    val[sidx] = tanhf(sum);
  }
  float drive = acc[0] + th[0];
#pragma unroll
  for (int j = 0; j < 16; ++j)
    if ((cm[0] >> j) & 1) drive += val[j] * ew[j];
  if (t < T_DATA) negd[t] = -drive;
}

// ---------------------------------------------------------------------------
// K4: sequential spike scan. 1 workgroup, 4 waves (one per SIMD).
// ROUND 13: R8/R12 chain kept EXACTLY; the boundary conv (64 fmas + 128
// SALU extracts, previously serialized between blocks because it consumed
// mask_prev) is now FUSED INTO THE CHAIN: each pair's already-materialized
// s0f/s1f also accumulate bnd0 += s0f*h(127-i), bnd1 += s1f*h(126-i) —
// independent accumulators, off the X-dependent chain, issued into the
// chain's hazard-stall slots. Next block starts X = deepb + bnd directly.
// Zero new registers; CH2's asm/selection untouched.
// ---------------------------------------------------------------------------
__global__
__attribute__((amdgpu_flat_work_group_size(256, 256), amdgpu_waves_per_eu(1, 1)))
void k_scan(
    const float* __restrict__ hist, const float* __restrict__ negd,
    float* __restrict__ out_spk) {
  __shared__ float hpad[328];        // [0..63]=0, [64..263]=h[0..199], [264..327]=0
  __shared__ unsigned long long mring[8];  // per-block spike masks, slot n&7
  __shared__ float deepb[2][3][64];  // parity double-buffered deep partials
  int tid = threadIdx.x, wid = tid >> 6, l = tid & 63;
  for (int i = tid; i < 328; i += 256) hpad[i] = (i >= 64 && i < 264) ? hist[i - 64] : 0.f;
  if (tid < 8) mring[tid] = 0ull;
  for (int i = tid; i < 2 * 3 * 64; i += 256) (&deepb[0][0][0])[i] = 0.f;
  __syncthreads();

  // wave0: h(j) = hpad[l + j].  chain step i adds h(63-i); boundary tap for
  // next block's lane l from step i's spike is h(127-i).
  float h0=0,h1=0,h2=0,h3=0,h4=0,h5=0,h6=0,h7=0,h8=0,h9=0,h10=0,h11=0,h12=0,h13=0,h14=0,h15=0,
        h16=0,h17=0,h18=0,h19=0,h20=0,h21=0,h22=0,h23=0,h24=0,h25=0,h26=0,h27=0,h28=0,h29=0,h30=0,h31=0,
        h32=0,h33=0,h34=0,h35=0,h36=0,h37=0,h38=0,h39=0,h40=0,h41=0,h42=0,h43=0,h44=0,h45=0,h46=0,h47=0,
        h48=0,h49=0,h50=0,h51=0,h52=0,h53=0,h54=0,h55=0,h56=0,h57=0,h58=0,h59=0,h60=0,h61=0,h62=0,h63=0,
        h64=0,h65=0,h66=0,h67=0,h68=0,h69=0,h70=0,h71=0,h72=0,h73=0,h74=0,h75=0,h76=0,h77=0,h78=0,h79=0,
        h80=0,h81=0,h82=0,h83=0,h84=0,h85=0,h86=0,h87=0,h88=0,h89=0,h90=0,h91=0,h92=0,h93=0,h94=0,h95=0,
        h96=0,h97=0,h98=0,h99=0,h100=0,h101=0,h102=0,h103=0,h104=0,h105=0,h106=0,h107=0,h108=0,h109=0,h110=0,h111=0,
        h112=0,h113=0,h114=0,h115=0,h116=0,h117=0,h118=0,h119=0,h120=0,h121=0,h122=0,h123=0,h124=0,h125=0,h126=0,h127=0;
  // deep-wave tap registers: hd(j) = hpad[dbase + l + j]
  float hd0=0,hd1=0,hd2=0,hd3=0,hd4=0,hd5=0,hd6=0,hd7=0,hd8=0,hd9=0,hd10=0,hd11=0,hd12=0,hd13=0,hd14=0,hd15=0,
        hd16=0,hd17=0,hd18=0,hd19=0,hd20=0,hd21=0,hd22=0,hd23=0,hd24=0,hd25=0,hd26=0,hd27=0,hd28=0,hd29=0,hd30=0,hd31=0,
        hd32=0,hd33=0,hd34=0,hd35=0,hd36=0,hd37=0,hd38=0,hd39=0,hd40=0,hd41=0,hd42=0,hd43=0,hd44=0,hd45=0;
  if (wid == 0) {
#define LD(j) h##j = hpad[l + j];
    LD(0)LD(1)LD(2)LD(3)LD(4)LD(5)LD(6)LD(7)LD(8)LD(9)LD(10)LD(11)LD(12)LD(13)LD(14)LD(15)
    LD(16)LD(17)LD(18)LD(19)LD(20)LD(21)LD(22)LD(23)LD(24)LD(25)LD(26)LD(27)LD(28)LD(29)LD(30)LD(31)
    LD(32)LD(33)LD(34)LD(35)LD(36)LD(37)LD(38)LD(39)LD(40)LD(41)LD(42)LD(43)LD(44)LD(45)LD(46)LD(47)
    LD(48)LD(49)LD(50)LD(51)LD(52)LD(53)LD(54)LD(55)LD(56)LD(57)LD(58)LD(59)LD(60)LD(61)LD(62)LD(63)
    LD(64)LD(65)LD(66)LD(67)LD(68)LD(69)LD(70)LD(71)LD(72)LD(73)LD(74)LD(75)LD(76)LD(77)LD(78)LD(79)
    LD(80)LD(81)LD(82)LD(83)LD(84)LD(85)LD(86)LD(87)LD(88)LD(89)LD(90)LD(91)LD(92)LD(93)LD(94)LD(95)
    LD(96)LD(97)LD(98)LD(99)LD(100)LD(101)LD(102)LD(103)LD(104)LD(105)LD(106)LD(107)LD(108)LD(109)LD(110)LD(111)
    LD(112)LD(113)LD(114)LD(115)LD(116)LD(117)LD(118)LD(119)LD(120)LD(121)LD(122)LD(123)LD(124)LD(125)LD(126)LD(127)
#undef LD
  } else {
    int dbase = (wid == 2) ? 174 : (wid == 3) ? 219 : 128;
#define LHD(j) hd##j = hpad[dbase + l + j];
    LHD(0)LHD(1)LHD(2)LHD(3)LHD(4)LHD(5)LHD(6)LHD(7)LHD(8)LHD(9)LHD(10)LHD(11)LHD(12)LHD(13)LHD(14)LHD(15)
    LHD(16)LHD(17)LHD(18)LHD(19)LHD(20)LHD(21)LHD(22)LHD(23)LHD(24)LHD(25)LHD(26)LHD(27)LHD(28)LHD(29)LHD(30)LHD(31)
    LHD(32)LHD(33)LHD(34)LHD(35)LHD(36)LHD(37)LHD(38)LHD(39)LHD(40)LHD(41)LHD(42)LHD(43)LHD(44)LHD(45)
#undef LHD
  }

  float bnd = 0.f;                   // next-block boundary feedback (wave0)
  float ndv = (wid == 0) ? negd[l] : 0.f;

  for (int n = 0; n < NBLK; ++n) {
    int t0 = n * 64;
    if (wid == 0) {
      int tn = t0 + 64 + l;
      float ndnext = (tn < T_DATA) ? negd[tn] : INFINITY;
      int par = n & 1;
      float X = deepb[par][0][l] + deepb[par][1][l] + deepb[par][2][l] + bnd;
      // 2-step lookahead chain: 32 pairs cover steps 0..63 (R8 idiom) with
      // fused boundary accumulation for the NEXT block.
      unsigned long long msk = 0ull;
      float bnd0 = 0.f, bnd1 = 0.f;
#define CH2(i, hvA, hvB, hbA, hbB) { \
      float Xa = X + hvA; \
      unsigned long long bm0, bm1; \
      asm("v_cmp_gt_f32 %0, %2, %4\n\t" \
          "v_cmp_gt_f32 %1, %3, %4" \
          : "=s"(bm0), "=s"(bm1) : "v"(X), "v"(Xa), "v"(ndv)); \
      unsigned s0b = (unsigned)(bm0 >> (i)) & 1u; \
      unsigned long long bmx = s0b ? bm1 : bm0; \
      unsigned s1b = (unsigned)(bmx >> ((i) + 1)) & 1u; \
      float s0f = (float)s0b, s1f = (float)s1b; \
      X = fmaf(s0f, hvA, X); \
      X = fmaf(s1f, hvB, X); \
      bnd0 = fmaf(s0f, hbA, bnd0); \
      bnd1 = fmaf(s1f, hbB, bnd1); \
      msk |= ((unsigned long long)s0b << (i)) | ((unsigned long long)s1b << ((i) + 1)); }
      CH2(0,h63,h62,h127,h126)  CH2(2,h61,h60,h125,h124)
      CH2(4,h59,h58,h123,h122)  CH2(6,h57,h56,h121,h120)
      CH2(8,h55,h54,h119,h118)  CH2(10,h53,h52,h117,h116)
      CH2(12,h51,h50,h115,h114) CH2(14,h49,h48,h113,h112)
      CH2(16,h47,h46,h111,h110) CH2(18,h45,h44,h109,h108)
      CH2(20,h43,h42,h107,h106) CH2(22,h41,h40,h105,h104)
      CH2(24,h39,h38,h103,h102) CH2(26,h37,h36,h101,h100)
      CH2(28,h35,h34,h99,h98)   CH2(30,h33,h32,h97,h96)
      CH2(32,h31,h30,h95,h94)   CH2(34,h29,h28,h93,h92)
      CH2(36,h27,h26,h91,h90)   CH2(38,h25,h24,h89,h88)
      CH2(40,h23,h22,h87,h86)   CH2(42,h21,h20,h85,h84)
      CH2(44,h19,h18,h83,h82)   CH2(46,h17,h16,h81,h80)
      CH2(48,h15,h14,h79,h78)   CH2(50,h13,h12,h77,h76)
      CH2(52,h11,h10,h75,h74)   CH2(54,h9,h8,h73,h72)
      CH2(56,h7,h6,h71,h70)     CH2(58,h5,h4,h69,h68)
      CH2(60,h3,h2,h67,h66)     CH2(62,h1,h0,h65,h64)
#undef CH2
      bnd = bnd0 + bnd1;
      // publish: spike output + block mask
      float myspk = (float)((msk >> l) & 1ull);
      int t = t0 + l;
      if (t < T_DATA) out_spk[t] = myspk;
      if (l == 0) mring[n & 7] = msk;
      ndv = ndnext;
    } else {
      // deep feedback for block n+1 from spike bitmasks of blocks n-1..n-3.
      unsigned long long M1 = mring[(n + 7) & 7];
      unsigned long long M2 = mring[(n + 6) & 7];
      unsigned long long M3 = mring[(n + 5) & 7];
      M1 = ((unsigned long long)__builtin_amdgcn_readfirstlane((unsigned)(M1 >> 32)) << 32)
           | (unsigned)__builtin_amdgcn_readfirstlane((unsigned)M1);
      M2 = ((unsigned long long)__builtin_amdgcn_readfirstlane((unsigned)(M2 >> 32)) << 32)
           | (unsigned)__builtin_amdgcn_readfirstlane((unsigned)M2);
      M3 = ((unsigned long long)__builtin_amdgcn_readfirstlane((unsigned)(M3 >> 32)) << 32)
           | (unsigned)__builtin_amdgcn_readfirstlane((unsigned)M3);
      float a0 = 0.f, a1 = 0.f, a2 = 0.f, a3 = 0.f;
#define DT(j, M, b, acc) acc = fmaf((float)(((M) >> (b)) & 1ull), hd##j, acc);
      if (wid == 1) {
        DT(0,M1,63,a0)DT(1,M1,62,a1)DT(2,M1,61,a2)DT(3,M1,60,a3)
        DT(4,M1,59,a0)DT(5,M1,58,a1)DT(6,M1,57,a2)DT(7,M1,56,a3)
        DT(8,M1,55,a0)DT(9,M1,54,a1)DT(10,M1,53,a2)DT(11,M1,52,a3)
        DT(12,M1,51,a0)DT(13,M1,50,a1)DT(14,M1,49,a2)DT(15,M1,48,a3)
        DT(16,M1,47,a0)DT(17,M1,46,a1)DT(18,M1,45,a2)DT(19,M1,44,a3)
        DT(20,M1,43,a0)DT(21,M1,42,a1)DT(22,M1,41,a2)DT(23,M1,40,a3)
        DT(24,M1,39,a0)DT(25,M1,38,a1)DT(26,M1,37,a2)DT(27,M1,36,a3)
        DT(28,M1,35,a0)DT(29,M1,34,a1)DT(30,M1,33,a2)DT(31,M1,32,a3)
        DT(32,M1,31,a0)DT(33,M1,30,a1)DT(34,M1,29,a2)DT(35,M1,28,a3)
        DT(36,M1,27,a0)DT(37,M1,26,a1)DT(38,M1,25,a2)DT(39,M1,24,a3)
        DT(40,M1,23,a0)DT(41,M1,22,a1)DT(42,M1,21,a2)DT(43,M1,20,a3)
        DT(44,M1,19,a0)DT(45,M1,18,a1)
      } else if (wid == 2) {
        DT(0,M1,17,a0)DT(1,M1,16,a1)DT(2,M1,15,a2)DT(3,M1,14,a3)
        DT(4,M1,13,a0)DT(5,M1,12,a1)DT(6,M1,11,a2)DT(7,M1,10,a3)
        DT(8,M1,9,a0)DT(9,M1,8,a1)DT(10,M1,7,a2)DT(11,M1,6,a3)
        DT(12,M1,5,a0)DT(13,M1,4,a1)DT(14,M1,3,a2)DT(15,M1,2,a3)
        DT(16,M1,1,a0)DT(17,M1,0,a1)
        DT(18,M2,63,a2)DT(19,M2,62,a3)
        DT(20,M2,61,a0)DT(21,M2,60,a1)DT(22,M2,59,a2)DT(23,M2,58,a3)
        DT(24,M2,57,a0)DT(25,M2,56,a1)DT(26,M2,55,a2)DT(27,M2,54,a3)
        DT(28,M2,53,a0)DT(29,M2,52,a1)DT(30,M2,51,a2)DT(31,M2,50,a3)
        DT(32,M2,49,a0)DT(33,M2,48,a1)DT(34,M2,47,a2)DT(35,M2,46,a3)
        DT(36,M2,45,a0)DT(37,M2,44,a1)DT(38,M2,43,a2)DT(39,M2,42,a3)
        DT(40,M2,41,a0)DT(41,M2,40,a1)DT(42,M2,39,a2)DT(43,M2,38,a3)
        DT(44,M2,37,a0)
      } else {
        DT(0,M2,36,a0)DT(1,M2,35,a1)DT(2,M2,34,a2)DT(3,M2,33,a3)
        DT(4,M2,32,a0)DT(5,M2,31,a1)DT(6,M2,30,a2)DT(7,M2,29,a3)
        DT(8,M2,28,a0)DT(9,M2,27,a1)DT(10,M2,26,a2)DT(11,M2,25,a3)
        DT(12,M2,24,a0)DT(13,M2,23,a1)DT(14,M2,22,a2)DT(15,M2,21,a3)
        DT(16,M2,20,a0)DT(17,M2,19,a1)DT(18,M2,18,a2)DT(19,M2,17,a3)
        DT(20,M2,16,a0)DT(21,M2,15,a1)DT(22,M2,14,a2)DT(23,M2,13,a3)
        DT(24,M2,12,a0)DT(25,M2,11,a1)DT(26,M2,10,a2)DT(27,M2,9,a3)
        DT(28,M2,8,a0)DT(29,M2,7,a1)DT(30,M2,6,a2)DT(31,M2,5,a3)
        DT(32,M2,4,a0)DT(33,M2,3,a1)DT(34,M2,2,a2)DT(35,M2,1,a3)
        DT(36,M2,0,a0)
        DT(37,M3,63,a1)DT(38,M3,62,a2)DT(39,M3,61,a3)
        DT(40,M3,60,a0)DT(41,M3,59,a1)DT(42,M3,58,a2)DT(43,M3,57,a3)
        DT(44,M3,56,a0)
      }
#undef DT
      deepb[(n + 1) & 1][wid - 1][l] = (a0 + a1) + (a2 + a3);
    }
    __syncthreads();
  }
}

// ---------------------------------------------------------------------------
extern "C" void kernel_launch(void* const* d_in, const int* in_sizes, int n_in,
                              void* d_out, int out_size, void* d_ws, size_t ws_size,
                              hipStream_t stream) {
  const float* S_e      = (const float*)d_in[0];
  const float* S_i      = (const float*)d_in[1];
  const int*   C_den    = (const int*)d_in[2];
  const float* C_syn_e  = (const float*)d_in[3];
  const float* C_syn_i  = (const float*)d_in[4];
  const float* cos_b    = (const float*)d_in[5];
  const float* Tau_e    = (const float*)d_in[6];
  const float* Tau_i    = (const float*)d_in[7];
  const float* W_e      = (const float*)d_in[8];
  const float* W_i      = (const float*)d_in[9];
  const float* D_e      = (const float*)d_in[10];
  const float* D_i      = (const float*)d_in[11];
  const float* W_sub    = (const float*)d_in[12];
  const float* W_hist   = (const float*)d_in[13];
  const float* Theta    = (const float*)d_in[14];
  float* out = (float*)d_out;

  float* wsf      = (float*)d_ws;
  float* ws_ek    = wsf;
  float* ws_ik    = wsf + 3200;
  float* ws_hist  = wsf + 6400;
  float* ws_ewsub = wsf + 6600;
  float* ws_we    = wsf + 6616;
  float* ws_wi    = wsf + 8616;
  float* synE     = wsf + 16384;
  float* synI     = wsf + 336384;
  float* negd     = wsf + 656384;
  int*   ws_me    = (int*)(wsf + 676384);
  int*   ws_mi    = (int*)(wsf + 678384);
  int*   ws_cmask = (int*)(wsf + 678884);

  k_prep<<<dim3(1), dim3(256), 0, stream>>>(
      C_syn_e, C_syn_i, cos_b, Tau_e, Tau_i, W_e, W_i, D_e, D_i, W_sub, W_hist,
      C_den, ws_ek, ws_ik, ws_hist, ws_ewsub, ws_we, ws_wi, ws_me, ws_mi,
      ws_cmask, out + T_DATA);

  k_agg<<<dim3(1250), dim3(256), 0, stream>>>(
      (const float4*)S_e, (const float4*)S_i, ws_me, ws_we, ws_mi, ws_wi,
      synE, synI);

  k_filt<<<dim3(NBLK), dim3(64), 0, stream>>>(
      synE, synI, ws_ek, ws_ik, Theta, ws_ewsub, ws_cmask, negd);

  k_scan<<<dim3(1), dim3(256), 0, stream>>>(ws_hist, negd, out);
}

// Round 14
// 693.507 us; speedup vs baseline: 2.0124x; 1.0084x over previous
//
#include <hip/hip_runtime.h>
#include <math.h>
#include <stdint.h>

#define T_DATA 20000
#define E_NO   2000
#define I_NO   500
#define SUB    16
#define TNO    200
#define NBLK   313   // ceil(20000/64)

// ---------------- workspace layout (float offsets) ----------------
// 0       ek[3200]   (s*200+t)
// 3200    ik[3200]
// 6400    hist[200]
// 6600    ewsub[16]
// 6616    we[2000]
// 8616    wi[500]
// 16384   synE[20000*16]
// 336384  synI[20000*16]
// 656384  negd[20000]
// 676384  me[2000] (int)
// 678384  mi[500]  (int)
// 678884  cmask[16](int)

// ---------------------------------------------------------------------------
// K1: per-subunit kernels, hist kernel, synapse->subunit maps, tree masks.
// ---------------------------------------------------------------------------
__global__ __launch_bounds__(256) void k_prep(
    const float* __restrict__ Ce, const float* __restrict__ Ci,
    const float* __restrict__ cosb,
    const float* __restrict__ TauE, const float* __restrict__ TauI,
    const float* __restrict__ We,  const float* __restrict__ Wi,
    const float* __restrict__ De,  const float* __restrict__ Di,
    const float* __restrict__ Wsub, const float* __restrict__ Whist,
    const int* __restrict__ Cden,
    float* __restrict__ ws_ek, float* __restrict__ ws_ik,
    float* __restrict__ ws_hist, float* __restrict__ ws_ewsub,
    float* __restrict__ ws_we, float* __restrict__ ws_wi,
    int* __restrict__ ws_me, int* __restrict__ ws_mi, int* __restrict__ ws_cmask,
    float* __restrict__ out_filt) {
  int tid = threadIdx.x;
  for (int idx = tid; idx < SUB * TNO; idx += 256) {
    int s = idx / TNO;
    float tf = (float)(idx % TNO);
    float te  = fmaxf(tf - expf(De[s]), 0.f);
    float tte = te / expf(TauE[s]);
    float ekv = tte * expf(-tte) * expf(We[s]);
    float ti_ = fmaxf(tf - expf(Di[s]), 0.f);
    float tti = ti_ / expf(TauI[s]);
    float ikv = -(tti * expf(-tti) * expf(Wi[s]));
    ws_ek[idx] = ekv;
    ws_ik[idx] = ikv;
    out_filt[idx] = ekv;            // rows 0..15
    out_filt[3200 + idx] = ikv;     // rows 16..31
  }
  for (int t = tid; t < TNO; t += 256) {
    float h = 0.f;
    for (int b = 0; b < 16; ++b) h = fmaf(Whist[b], cosb[b * TNO + t], h);
    ws_hist[t] = h;
    out_filt[6400 + t] = h;         // row 32 (unflipped)
  }
  for (int e = tid; e < E_NO; e += 256) {
    int m = 0; float w = 0.f;
    for (int s = 0; s < SUB; ++s) {
      float v = Ce[s * E_NO + e];
      if (w == 0.f && v != 0.f) { m = s; w = v; }
    }
    ws_me[e] = m; ws_we[e] = w;
  }
  for (int e = tid; e < I_NO; e += 256) {
    int m = 0; float w = 0.f;
    for (int s = 0; s < SUB; ++s) {
      float v = Ci[s * I_NO + e];
      if (w == 0.f && v != 0.f) { m = s; w = v; }
    }
    ws_mi[e] = m; ws_wi[e] = w;
  }
  if (tid < SUB) {
    ws_ewsub[tid] = expf(Wsub[tid]);
    int msk = 0;
    for (int j = 0; j < SUB; ++j)
      if (Cden[tid * SUB + j] == 1) msk |= (1 << j);
    ws_cmask[tid] = msk;
  }
}

// ---------------------------------------------------------------------------
// K2: synapse aggregation -> synE/synI [20000][16]. Deterministic.
// ---------------------------------------------------------------------------
__global__ __launch_bounds__(256) void k_agg(
    const float4* __restrict__ Se4, const float4* __restrict__ Si4,
    const int* __restrict__ me, const float* __restrict__ we,
    const int* __restrict__ mi, const float* __restrict__ wi,
    float* __restrict__ synE, float* __restrict__ synI) {
  __shared__ float bins[4][64][33];
  int tid = threadIdx.x, wid = tid >> 6, l = tid & 63;
  int gw = blockIdx.x * 4 + wid;
  for (int r = 0; r < 4; ++r) {
    int t = gw * 4 + r;
#pragma unroll
    for (int s = 0; s < 32; ++s) bins[wid][l][s] = 0.f;
    for (int i = 0; i < 8; ++i) {
      int idx = i * 64 + l;
      if (idx < 500) {
        float4 v = Se4[(size_t)t * 500 + idx];
        int e0 = idx * 4;
        if (v.x != 0.f) bins[wid][l][me[e0 + 0]] += v.x * we[e0 + 0];
        if (v.y != 0.f) bins[wid][l][me[e0 + 1]] += v.y * we[e0 + 1];
        if (v.z != 0.f) bins[wid][l][me[e0 + 2]] += v.z * we[e0 + 2];
        if (v.w != 0.f) bins[wid][l][me[e0 + 3]] += v.w * we[e0 + 3];
      }
    }
    for (int i = 0; i < 2; ++i) {
      int idx = i * 64 + l;
      if (idx < 125) {
        float4 v = Si4[(size_t)t * 125 + idx];
        int e0 = idx * 4;
        if (v.x != 0.f) bins[wid][l][16 + mi[e0 + 0]] += v.x * wi[e0 + 0];
        if (v.y != 0.f) bins[wid][l][16 + mi[e0 + 1]] += v.y * wi[e0 + 1];
        if (v.z != 0.f) bins[wid][l][16 + mi[e0 + 2]] += v.z * wi[e0 + 2];
        if (v.w != 0.f) bins[wid][l][16 + mi[e0 + 3]] += v.w * wi[e0 + 3];
      }
    }
    __syncthreads();
    if (l < 32) {
      float a = 0.f;
      for (int k = 0; k < 64; ++k) a += bins[wid][k][l];
      if (l < 16) synE[(size_t)t * 16 + l] = a;
      else        synI[(size_t)t * 16 + (l - 16)] = a;
    }
    __syncthreads();
  }
}

// ---------------------------------------------------------------------------
// K3: causal filtering + dendritic tree -> negd[t] = -drive[t].
// ---------------------------------------------------------------------------
__global__ __launch_bounds__(64) void k_filt(
    const float* __restrict__ synE, const float* __restrict__ synI,
    const float* __restrict__ ek_ws, const float* __restrict__ ik_ws,
    const float* __restrict__ theta, const float* __restrict__ ewsub,
    const int* __restrict__ cmask,
    float* __restrict__ negd) {
  __shared__ float sE[264 * 17];
  __shared__ float sI[264 * 17];
  __shared__ float ekl[TNO * 16];
  __shared__ float ikl[TNO * 16];
  int l = threadIdx.x;
  int t0 = blockIdx.x * 64;
  for (int idx = l; idx < 264 * 16; idx += 64) {
    int row = idx >> 4, s = idx & 15;
    int g = t0 - 200 + row;
    bool ok = (g >= 0) && (g < T_DATA);
    sE[row * 17 + s] = ok ? synE[(size_t)g * 16 + s] : 0.f;
    sI[row * 17 + s] = ok ? synI[(size_t)g * 16 + s] : 0.f;
  }
  for (int idx = l; idx < SUB * TNO; idx += 64) {
    int s = idx / TNO, j = idx % TNO;
    ekl[j * 16 + s] = ek_ws[idx];
    ikl[j * 16 + s] = ik_ws[idx];
  }
  __syncthreads();
  int t = t0 + l;
  float acc[16];
#pragma unroll
  for (int s = 0; s < 16; ++s) acc[s] = 0.f;
  for (int j = 0; j < TNO; ++j) {
    int base = (l + 199 - j) * 17;
    int kb = j * 16;
#pragma unroll
    for (int s = 0; s < 16; ++s)
      acc[s] = fmaf(ekl[kb + s], sE[base + s], fmaf(ikl[kb + s], sI[base + s], acc[s]));
  }
  float th[16], ew[16]; int cm[16];
#pragma unroll
  for (int s = 0; s < 16; ++s) { th[s] = theta[s]; ew[s] = ewsub[s]; cm[s] = cmask[s]; }
  float val[16];
#pragma unroll
  for (int s = 0; s < 16; ++s) val[s] = 0.f;
#pragma unroll
  for (int sidx = 15; sidx >= 1; --sidx) {
    float sum = acc[sidx] + th[sidx];
#pragma unroll
    for (int j = 0; j < 16; ++j)
      if ((cm[sidx] >> j) & 1) sum += val[j] * ew[j];
    val[sidx] = tanhf(sum);
  }
  float drive = acc[0] + th[0];
#pragma unroll
  for (int j = 0; j < 16; ++j)
    if ((cm[0] >> j) & 1) drive += val[j] * ew[j];
  if (t < T_DATA) negd[t] = -drive;
}

// ---------------------------------------------------------------------------
// K4: sequential spike scan. 1 workgroup, 4 waves (one per SIMD).
// ROUND 14: R13 kept EXACTLY, plus per-pair THRESHOLD PRECOMPUTE:
// X + hA > ndv  <=>  X > ndv - hA, and ndv - hA is block-invariant. The 32
// thresholds ta_p live in registers; both v_cmp now take X directly and
// issue back-to-back the moment X is ready — the serial leading add leaves
// the chain. Thresholds refresh off-chain (ta_p = ndnext - hA after use,
// same stall-slot trick as R13's bnd fusion). CH2 asm/selection unchanged.
// ---------------------------------------------------------------------------
__global__
__attribute__((amdgpu_flat_work_group_size(256, 256), amdgpu_waves_per_eu(1, 1)))
void k_scan(
    const float* __restrict__ hist, const float* __restrict__ negd,
    float* __restrict__ out_spk) {
  __shared__ float hpad[328];        // [0..63]=0, [64..263]=h[0..199], [264..327]=0
  __shared__ unsigned long long mring[8];  // per-block spike masks, slot n&7
  __shared__ float deepb[2][3][64];  // parity double-buffered deep partials
  int tid = threadIdx.x, wid = tid >> 6, l = tid & 63;
  for (int i = tid; i < 328; i += 256) hpad[i] = (i >= 64 && i < 264) ? hist[i - 64] : 0.f;
  if (tid < 8) mring[tid] = 0ull;
  for (int i = tid; i < 2 * 3 * 64; i += 256) (&deepb[0][0][0])[i] = 0.f;
  __syncthreads();

  // wave0: h(j) = hpad[l + j].  chain step i adds h(63-i); boundary tap for
  // next block's lane l from step i's spike is h(127-i).
  float h0=0,h1=0,h2=0,h3=0,h4=0,h5=0,h6=0,h7=0,h8=0,h9=0,h10=0,h11=0,h12=0,h13=0,h14=0,h15=0,
        h16=0,h17=0,h18=0,h19=0,h20=0,h21=0,h22=0,h23=0,h24=0,h25=0,h26=0,h27=0,h28=0,h29=0,h30=0,h31=0,
        h32=0,h33=0,h34=0,h35=0,h36=0,h37=0,h38=0,h39=0,h40=0,h41=0,h42=0,h43=0,h44=0,h45=0,h46=0,h47=0,
        h48=0,h49=0,h50=0,h51=0,h52=0,h53=0,h54=0,h55=0,h56=0,h57=0,h58=0,h59=0,h60=0,h61=0,h62=0,h63=0,
        h64=0,h65=0,h66=0,h67=0,h68=0,h69=0,h70=0,h71=0,h72=0,h73=0,h74=0,h75=0,h76=0,h77=0,h78=0,h79=0,
        h80=0,h81=0,h82=0,h83=0,h84=0,h85=0,h86=0,h87=0,h88=0,h89=0,h90=0,h91=0,h92=0,h93=0,h94=0,h95=0,
        h96=0,h97=0,h98=0,h99=0,h100=0,h101=0,h102=0,h103=0,h104=0,h105=0,h106=0,h107=0,h108=0,h109=0,h110=0,h111=0,
        h112=0,h113=0,h114=0,h115=0,h116=0,h117=0,h118=0,h119=0,h120=0,h121=0,h122=0,h123=0,h124=0,h125=0,h126=0,h127=0;
  // per-pair no->spike thresholds: ta_p = ndv - h(63-2p)
  float ta0=0,ta1=0,ta2=0,ta3=0,ta4=0,ta5=0,ta6=0,ta7=0,
        ta8=0,ta9=0,ta10=0,ta11=0,ta12=0,ta13=0,ta14=0,ta15=0,
        ta16=0,ta17=0,ta18=0,ta19=0,ta20=0,ta21=0,ta22=0,ta23=0,
        ta24=0,ta25=0,ta26=0,ta27=0,ta28=0,ta29=0,ta30=0,ta31=0;
  // deep-wave tap registers: hd(j) = hpad[dbase + l + j]
  float hd0=0,hd1=0,hd2=0,hd3=0,hd4=0,hd5=0,hd6=0,hd7=0,hd8=0,hd9=0,hd10=0,hd11=0,hd12=0,hd13=0,hd14=0,hd15=0,
        hd16=0,hd17=0,hd18=0,hd19=0,hd20=0,hd21=0,hd22=0,hd23=0,hd24=0,hd25=0,hd26=0,hd27=0,hd28=0,hd29=0,hd30=0,hd31=0,
        hd32=0,hd33=0,hd34=0,hd35=0,hd36=0,hd37=0,hd38=0,hd39=0,hd40=0,hd41=0,hd42=0,hd43=0,hd44=0,hd45=0;
  if (wid == 0) {
#define LD(j) h##j = hpad[l + j];
    LD(0)LD(1)LD(2)LD(3)LD(4)LD(5)LD(6)LD(7)LD(8)LD(9)LD(10)LD(11)LD(12)LD(13)LD(14)LD(15)
    LD(16)LD(17)LD(18)LD(19)LD(20)LD(21)LD(22)LD(23)LD(24)LD(25)LD(26)LD(27)LD(28)LD(29)LD(30)LD(31)
    LD(32)LD(33)LD(34)LD(35)LD(36)LD(37)LD(38)LD(39)LD(40)LD(41)LD(42)LD(43)LD(44)LD(45)LD(46)LD(47)
    LD(48)LD(49)LD(50)LD(51)LD(52)LD(53)LD(54)LD(55)LD(56)LD(57)LD(58)LD(59)LD(60)LD(61)LD(62)LD(63)
    LD(64)LD(65)LD(66)LD(67)LD(68)LD(69)LD(70)LD(71)LD(72)LD(73)LD(74)LD(75)LD(76)LD(77)LD(78)LD(79)
    LD(80)LD(81)LD(82)LD(83)LD(84)LD(85)LD(86)LD(87)LD(88)LD(89)LD(90)LD(91)LD(92)LD(93)LD(94)LD(95)
    LD(96)LD(97)LD(98)LD(99)LD(100)LD(101)LD(102)LD(103)LD(104)LD(105)LD(106)LD(107)LD(108)LD(109)LD(110)LD(111)
    LD(112)LD(113)LD(114)LD(115)LD(116)LD(117)LD(118)LD(119)LD(120)LD(121)LD(122)LD(123)LD(124)LD(125)LD(126)LD(127)
#undef LD
  } else {
    int dbase = (wid == 2) ? 174 : (wid == 3) ? 219 : 128;
#define LHD(j) hd##j = hpad[dbase + l + j];
    LHD(0)LHD(1)LHD(2)LHD(3)LHD(4)LHD(5)LHD(6)LHD(7)LHD(8)LHD(9)LHD(10)LHD(11)LHD(12)LHD(13)LHD(14)LHD(15)
    LHD(16)LHD(17)LHD(18)LHD(19)LHD(20)LHD(21)LHD(22)LHD(23)LHD(24)LHD(25)LHD(26)LHD(27)LHD(28)LHD(29)LHD(30)LHD(31)
    LHD(32)LHD(33)LHD(34)LHD(35)LHD(36)LHD(37)LHD(38)LHD(39)LHD(40)LHD(41)LHD(42)LHD(43)LHD(44)LHD(45)
#undef LHD
  }

  float bnd = 0.f;                   // next-block boundary feedback (wave0)
  float ndv = (wid == 0) ? negd[l] : 0.f;
  if (wid == 0) {
    ta0 = ndv - h63;  ta1 = ndv - h61;  ta2 = ndv - h59;  ta3 = ndv - h57;
    ta4 = ndv - h55;  ta5 = ndv - h53;  ta6 = ndv - h51;  ta7 = ndv - h49;
    ta8 = ndv - h47;  ta9 = ndv - h45;  ta10 = ndv - h43; ta11 = ndv - h41;
    ta12 = ndv - h39; ta13 = ndv - h37; ta14 = ndv - h35; ta15 = ndv - h33;
    ta16 = ndv - h31; ta17 = ndv - h29; ta18 = ndv - h27; ta19 = ndv - h25;
    ta20 = ndv - h23; ta21 = ndv - h21; ta22 = ndv - h19; ta23 = ndv - h17;
    ta24 = ndv - h15; ta25 = ndv - h13; ta26 = ndv - h11; ta27 = ndv - h9;
    ta28 = ndv - h7;  ta29 = ndv - h5;  ta30 = ndv - h3;  ta31 = ndv - h1;
  }

  for (int n = 0; n < NBLK; ++n) {
    int t0 = n * 64;
    if (wid == 0) {
      int tn = t0 + 64 + l;
      float ndnext = (tn < T_DATA) ? negd[tn] : INFINITY;
      int par = n & 1;
      float X = deepb[par][0][l] + deepb[par][1][l] + deepb[par][2][l] + bnd;
      // 2-step lookahead chain: 32 pairs, thresholds precomputed, boundary
      // accumulation fused (R13), threshold refresh fused (R14).
      unsigned long long msk = 0ull;
      float bnd0 = 0.f, bnd1 = 0.f;
#define CH2(p, i, hvA, hvB, hbA, hbB) { \
      unsigned long long bm0, bm1; \
      asm("v_cmp_gt_f32 %0, %2, %3\n\t" \
          "v_cmp_gt_f32 %1, %2, %4" \
          : "=s"(bm0), "=s"(bm1) : "v"(X), "v"(ndv), "v"(ta##p)); \
      unsigned s0b = (unsigned)(bm0 >> (i)) & 1u; \
      unsigned long long bmx = s0b ? bm1 : bm0; \
      unsigned s1b = (unsigned)(bmx >> ((i) + 1)) & 1u; \
      float s0f = (float)s0b, s1f = (float)s1b; \
      X = fmaf(s0f, hvA, X); \
      X = fmaf(s1f, hvB, X); \
      bnd0 = fmaf(s0f, hbA, bnd0); \
      bnd1 = fmaf(s1f, hbB, bnd1); \
      ta##p = ndnext - hvA; \
      msk |= ((unsigned long long)s0b << (i)) | ((unsigned long long)s1b << ((i) + 1)); }
      CH2(0,0,h63,h62,h127,h126)   CH2(1,2,h61,h60,h125,h124)
      CH2(2,4,h59,h58,h123,h122)   CH2(3,6,h57,h56,h121,h120)
      CH2(4,8,h55,h54,h119,h118)   CH2(5,10,h53,h52,h117,h116)
      CH2(6,12,h51,h50,h115,h114)  CH2(7,14,h49,h48,h113,h112)
      CH2(8,16,h47,h46,h111,h110)  CH2(9,18,h45,h44,h109,h108)
      CH2(10,20,h43,h42,h107,h106) CH2(11,22,h41,h40,h105,h104)
      CH2(12,24,h39,h38,h103,h102) CH2(13,26,h37,h36,h101,h100)
      CH2(14,28,h35,h34,h99,h98)   CH2(15,30,h33,h32,h97,h96)
      CH2(16,32,h31,h30,h95,h94)   CH2(17,34,h29,h28,h93,h92)
      CH2(18,36,h27,h26,h91,h90)   CH2(19,38,h25,h24,h89,h88)
      CH2(20,40,h23,h22,h87,h86)   CH2(21,42,h21,h20,h85,h84)
      CH2(22,44,h19,h18,h83,h82)   CH2(23,46,h17,h16,h81,h80)
      CH2(24,48,h15,h14,h79,h78)   CH2(25,50,h13,h12,h77,h76)
      CH2(26,52,h11,h10,h75,h74)   CH2(27,54,h9,h8,h73,h72)
      CH2(28,56,h7,h6,h71,h70)     CH2(29,58,h5,h4,h69,h68)
      CH2(30,60,h3,h2,h67,h66)     CH2(31,62,h1,h0,h65,h64)
#undef CH2
      bnd = bnd0 + bnd1;
      // publish: spike output + block mask
      float myspk = (float)((msk >> l) & 1ull);
      int t = t0 + l;
      if (t < T_DATA) out_spk[t] = myspk;
      if (l == 0) mring[n & 7] = msk;
      ndv = ndnext;
    } else {
      // deep feedback for block n+1 from spike bitmasks of blocks n-1..n-3.
      unsigned long long M1 = mring[(n + 7) & 7];
      unsigned long long M2 = mring[(n + 6) & 7];
      unsigned long long M3 = mring[(n + 5) & 7];
      M1 = ((unsigned long long)__builtin_amdgcn_readfirstlane((unsigned)(M1 >> 32)) << 32)
           | (unsigned)__builtin_amdgcn_readfirstlane((unsigned)M1);
      M2 = ((unsigned long long)__builtin_amdgcn_readfirstlane((unsigned)(M2 >> 32)) << 32)
           | (unsigned)__builtin_amdgcn_readfirstlane((unsigned)M2);
      M3 = ((unsigned long long)__builtin_amdgcn_readfirstlane((unsigned)(M3 >> 32)) << 32)
           | (unsigned)__builtin_amdgcn_readfirstlane((unsigned)M3);
      float a0 = 0.f, a1 = 0.f, a2 = 0.f, a3 = 0.f;
#define DT(j, M, b, acc) acc = fmaf((float)(((M) >> (b)) & 1ull), hd##j, acc);
      if (wid == 1) {
        DT(0,M1,63,a0)DT(1,M1,62,a1)DT(2,M1,61,a2)DT(3,M1,60,a3)
        DT(4,M1,59,a0)DT(5,M1,58,a1)DT(6,M1,57,a2)DT(7,M1,56,a3)
        DT(8,M1,55,a0)DT(9,M1,54,a1)DT(10,M1,53,a2)DT(11,M1,52,a3)
        DT(12,M1,51,a0)DT(13,M1,50,a1)DT(14,M1,49,a2)DT(15,M1,48,a3)
        DT(16,M1,47,a0)DT(17,M1,46,a1)DT(18,M1,45,a2)DT(19,M1,44,a3)
        DT(20,M1,43,a0)DT(21,M1,42,a1)DT(22,M1,41,a2)DT(23,M1,40,a3)
        DT(24,M1,39,a0)DT(25,M1,38,a1)DT(26,M1,37,a2)DT(27,M1,36,a3)
        DT(28,M1,35,a0)DT(29,M1,34,a1)DT(30,M1,33,a2)DT(31,M1,32,a3)
        DT(32,M1,31,a0)DT(33,M1,30,a1)DT(34,M1,29,a2)DT(35,M1,28,a3)
        DT(36,M1,27,a0)DT(37,M1,26,a1)DT(38,M1,25,a2)DT(39,M1,24,a3)
        DT(40,M1,23,a0)DT(41,M1,22,a1)DT(42,M1,21,a2)DT(43,M1,20,a3)
        DT(44,M1,19,a0)DT(45,M1,18,a1)
      } else if (wid == 2) {
        DT(0,M1,17,a0)DT(1,M1,16,a1)DT(2,M1,15,a2)DT(3,M1,14,a3)
        DT(4,M1,13,a0)DT(5,M1,12,a1)DT(6,M1,11,a2)DT(7,M1,10,a3)
        DT(8,M1,9,a0)DT(9,M1,8,a1)DT(10,M1,7,a2)DT(11,M1,6,a3)
        DT(12,M1,5,a0)DT(13,M1,4,a1)DT(14,M1,3,a2)DT(15,M1,2,a3)
        DT(16,M1,1,a0)DT(17,M1,0,a1)
        DT(18,M2,63,a2)DT(19,M2,62,a3)
        DT(20,M2,61,a0)DT(21,M2,60,a1)DT(22,M2,59,a2)DT(23,M2,58,a3)
        DT(24,M2,57,a0)DT(25,M2,56,a1)DT(26,M2,55,a2)DT(27,M2,54,a3)
        DT(28,M2,53,a0)DT(29,M2,52,a1)DT(30,M2,51,a2)DT(31,M2,50,a3)
        DT(32,M2,49,a0)DT(33,M2,48,a1)DT(34,M2,47,a2)DT(35,M2,46,a3)
        DT(36,M2,45,a0)DT(37,M2,44,a1)DT(38,M2,43,a2)DT(39,M2,42,a3)
        DT(40,M2,41,a0)DT(41,M2,40,a1)DT(42,M2,39,a2)DT(43,M2,38,a3)
        DT(44,M2,37,a0)
      } else {
        DT(0,M2,36,a0)DT(1,M2,35,a1)DT(2,M2,34,a2)DT(3,M2,33,a3)
        DT(4,M2,32,a0)DT(5,M2,31,a1)DT(6,M2,30,a2)DT(7,M2,29,a3)
        DT(8,M2,28,a0)DT(9,M2,27,a1)DT(10,M2,26,a2)DT(11,M2,25,a3)
        DT(12,M2,24,a0)DT(13,M2,23,a1)DT(14,M2,22,a2)DT(15,M2,21,a3)
        DT(16,M2,20,a0)DT(17,M2,19,a1)DT(18,M2,18,a2)DT(19,M2,17,a3)
        DT(20,M2,16,a0)DT(21,M2,15,a1)DT(22,M2,14,a2)DT(23,M2,13,a3)
        DT(24,M2,12,a0)DT(25,M2,11,a1)DT(26,M2,10,a2)DT(27,M2,9,a3)
        DT(28,M2,8,a0)DT(29,M2,7,a1)DT(30,M2,6,a2)DT(31,M2,5,a3)
        DT(32,M2,4,a0)DT(33,M2,3,a1)DT(34,M2,2,a2)DT(35,M2,1,a3)
        DT(36,M2,0,a0)
        DT(37,M3,63,a1)DT(38,M3,62,a2)DT(39,M3,61,a3)
        DT(40,M3,60,a0)DT(41,M3,59,a1)DT(42,M3,58,a2)DT(43,M3,57,a3)
        DT(44,M3,56,a0)
      }
#undef DT
      deepb[(n + 1) & 1][wid - 1][l] = (a0 + a1) + (a2 + a3);
    }
    __syncthreads();
  }
}

// ---------------------------------------------------------------------------
extern "C" void kernel_launch(void* const* d_in, const int* in_sizes, int n_in,
                              void* d_out, int out_size, void* d_ws, size_t ws_size,
                              hipStream_t stream) {
  const float* S_e      = (const float*)d_in[0];
  const float* S_i      = (const float*)d_in[1];
  const int*   C_den    = (const int*)d_in[2];
  const float* C_syn_e  = (const float*)d_in[3];
  const float* C_syn_i  = (const float*)d_in[4];
  const float* cos_b    = (const float*)d_in[5];
  const float* Tau_e    = (const float*)d_in[6];
  const float* Tau_i    = (const float*)d_in[7];
  const float* W_e      = (const float*)d_in[8];
  const float* W_i      = (const float*)d_in[9];
  const float* D_e      = (const float*)d_in[10];
  const float* D_i      = (const float*)d_in[11];
  const float* W_sub    = (const float*)d_in[12];
  const float* W_hist   = (const float*)d_in[13];
  const float* Theta    = (const float*)d_in[14];
  float* out = (float*)d_out;

  float* wsf      = (float*)d_ws;
  float* ws_ek    = wsf;
  float* ws_ik    = wsf + 3200;
  float* ws_hist  = wsf + 6400;
  float* ws_ewsub = wsf + 6600;
  float* ws_we    = wsf + 6616;
  float* ws_wi    = wsf + 8616;
  float* synE     = wsf + 16384;
  float* synI     = wsf + 336384;
  float* negd     = wsf + 656384;
  int*   ws_me    = (int*)(wsf + 676384);
  int*   ws_mi    = (int*)(wsf + 678384);
  int*   ws_cmask = (int*)(wsf + 678884);

  k_prep<<<dim3(1), dim3(256), 0, stream>>>(
      C_syn_e, C_syn_i, cos_b, Tau_e, Tau_i, W_e, W_i, D_e, D_i, W_sub, W_hist,
      C_den, ws_ek, ws_ik, ws_hist, ws_ewsub, ws_we, ws_wi, ws_me, ws_mi,
      ws_cmask, out + T_DATA);

  k_agg<<<dim3(1250), dim3(256), 0, stream>>>(
      (const float4*)S_e, (const float4*)S_i, ws_me, ws_we, ws_mi, ws_wi,
      synE, synI);

  k_filt<<<dim3(NBLK), dim3(64), 0, stream>>>(
      synE, synI, ws_ek, ws_ik, Theta, ws_ewsub, ws_cmask, negd);

  k_scan<<<dim3(1), dim3(256), 0, stream>>>(ws_hist, negd, out);
}